// Round 14
// baseline (300.271 us; speedup 1.0000x reference)
//
#include <hip/hip_runtime.h>
#include <hip/hip_bf16.h>
#include <math.h>

#define EPS 1e-5f
#define ST 896                   // padded Bmap row stride (fp16 elems), 64B-multiple
#define PLANE (896 * 806)        // padded plane elems (3+800+3 rows)
#define PLANE4 (PLANE / 8)       // uint4 per plane = 90272

typedef _Float16 f16x8 __attribute__((ext_vector_type(8)));
typedef _Float16 h2 __attribute__((ext_vector_type(2)));
typedef float f32x4 __attribute__((ext_vector_type(4)));

__device__ __forceinline__ float elu_f(float x) {
    return x > 0.f ? x : __expf(x) - 1.f;
}
__device__ __forceinline__ unsigned short f16b(float x) {
    return __builtin_bit_cast(unsigned short, (_Float16)x);
}

// ---- Merged prep ----
// b<100:      kembed via MFMA (16 z-rows/block, e fp16 rows padded to 112)
// 100..163:   kprepW (W1 -> fp16 B-fragments, K=256 split-K layout)
// 164..1232:  kzero  (halo borders of padded Bmap)
// 1233..1235: W2pack (dual-alignment fp16 weight quads)
__global__ __launch_bounds__(256) void kprep(const float* __restrict__ z0,
                                             const float* __restrict__ z1,
                                             const float* __restrict__ Wemb,
                                             const float* __restrict__ bemb,
                                             unsigned short* __restrict__ e0h,
                                             unsigned short* __restrict__ e1h,
                                             const float* __restrict__ W1,
                                             unsigned short* __restrict__ Bh,
                                             unsigned short* __restrict__ Bmap,
                                             const float* __restrict__ W2,
                                             unsigned short* __restrict__ Wq) {
    __shared__ unsigned short zls[16][1032];   // 16 z-rows fp16, padded stride
    int b = blockIdx.x;
    int tid = threadIdx.x;
    if (b < 100) {
        // ---- kembed MFMA: e[m][d] = elu(z[m][:] . Wemb[d][:] + bemb[d]) ----
        int src = b & 1;
        int rowbase = (b >> 1) * 16;
        const float* z = src ? z1 : z0;
        unsigned short* e = src ? e1h : e0h;
        const float4* zr4 = (const float4*)(z + rowbase * 1024);
        for (int idx = tid; idx < 4096; idx += 256) {
            int r = idx >> 8, c = idx & 255;
            float4 v = zr4[idx];
            unsigned int p0 = __builtin_bit_cast(unsigned int,
                __builtin_amdgcn_cvt_pkrtz(v.x, v.y));
            unsigned int p1 = __builtin_bit_cast(unsigned int,
                __builtin_amdgcn_cvt_pkrtz(v.z, v.w));
            uint2 pv = {p0, p1};
            *(uint2*)&zls[r][c * 4] = pv;
        }
        __syncthreads();
        int lane = tid & 63, wid = tid >> 6;
        int g = lane >> 4, rl = lane & 15;
        int mf0 = wid * 2;
        int nfrag = (wid < 3) ? 2 : 1;      // 7 d-frags over 4 waves
        f32x4 acc[2] = {};
        for (int ks = 0; ks < 32; ++ks) {
            f16x8 bz = *(const f16x8*)&zls[rl][ks * 32 + g * 8];
#pragma unroll
            for (int q = 0; q < 2; ++q) {
                if (q < nfrag) {
                    int d = (mf0 + q) * 16 + rl;
                    d = d > 99 ? 99 : d;
                    const float* wp = Wemb + d * 1024 + ks * 32 + g * 8;
                    float4 w0 = *(const float4*)wp;
                    float4 w1 = *(const float4*)(wp + 4);
                    uint4 au;
                    au.x = __builtin_bit_cast(unsigned int,
                        __builtin_amdgcn_cvt_pkrtz(w0.x, w0.y));
                    au.y = __builtin_bit_cast(unsigned int,
                        __builtin_amdgcn_cvt_pkrtz(w0.z, w0.w));
                    au.z = __builtin_bit_cast(unsigned int,
                        __builtin_amdgcn_cvt_pkrtz(w1.x, w1.y));
                    au.w = __builtin_bit_cast(unsigned int,
                        __builtin_amdgcn_cvt_pkrtz(w1.z, w1.w));
                    f16x8 a = __builtin_bit_cast(f16x8, au);
                    acc[q] = __builtin_amdgcn_mfma_f32_16x16x32_f16(a, bz, acc[q], 0, 0, 0);
                }
            }
        }
#pragma unroll
        for (int q = 0; q < 2; ++q) {
            if (q < nfrag) {
                int dbase = (mf0 + q) * 16 + g * 4;
                int zr = rowbase + rl;
                unsigned short o[4];
#pragma unroll
                for (int r = 0; r < 4; ++r) {
                    int d = dbase + r;
                    float be = bemb[d > 99 ? 99 : d];
                    float x = elu_f(acc[q][r] + be);
                    o[r] = (d < 100) ? f16b(x) : (unsigned short)0;
                }
                *(ushort4*)&e[zr * 112 + dbase] = *(ushort4*)o;
            }
        }
    } else if (b < 164) {
        // ---- kprepW: fp16 B-fragments; K=256: k<128 dif(d=k), k>=128 mul(d=k-128) ----
        int idx = (b - 100) * 256 + tid;     // 0..16383
        int i = idx & 7;
        int lane = (idx >> 3) & 63;
        int hf = (idx >> 9) & 3;
        int ks = idx >> 11;                  // 0..7
        int h = hf * 16 + (lane & 15);
        int k = ks * 32 + (lane >> 4) * 8 + i;
        int term = k >> 7;
        int d = k & 127;
        float val = (d < 100 && h < 50) ? W1[h * 200 + term * 100 + d] : 0.f;
        Bh[idx] = f16b(val);
    } else if (b < 1233) {
        // ---- kzero: halo borders of padded Bmap (uint4) ----
        int idx = (b - 164) * 256 + tid;
        if (idx < 273600) {
            int h = idx / 5472, q = idx % 5472;
            int row, colv;
            if (q < 672) {
                int rr = q / 112;
                colv = q - rr * 112;
                row = rr < 3 ? rr : 800 + rr;
            } else {
                int q2 = q - 672;
                row = 3 + q2 / 6;
                int s = q2 % 6;
                colv = (s == 0) ? 3 : 103 + s;
            }
            uint4 zz = {0, 0, 0, 0};
            ((uint4*)Bmap)[(size_t)h * PLANE4 + row * 112 + colv] = zz;
        }
    } else {
        // ---- W2 pack: dual-alignment fp16 weight quads for dot2 conv ----
        int idx = (b - 1233) * 256 + tid;
        if (idx < 700) {
            int h = idx / 14, rem = idx % 14;
            int lay = rem / 7, di = rem % 7;
            const float* wsrc = W2 + h * 49 + di * 7;
            unsigned short wf[8];
            if (lay == 0) {
#pragma unroll
                for (int t = 0; t < 7; t++) wf[t] = f16b(wsrc[t]);
                wf[7] = 0;
            } else {
                wf[0] = 0;
#pragma unroll
                for (int t = 0; t < 7; t++) wf[t + 1] = f16b(wsrc[t]);
            }
            *(uint4*)&Wq[idx * 8] = *(uint4*)wf;
        }
    }
}

// ---------------- Kernel 2: interaction GEMM via MFMA (fp16, split-K 256) ----------------
// grid (200,25), 256 thr = 4 waves. Tile 4 i x 32 j; each wave owns ONE i.
// Per-lane acc = 32 f32 (acc[jf][hf]); bn consts via LDS table.
__global__ __launch_bounds__(256, 6) void kinter(const unsigned short* __restrict__ e0h,
                                                 const unsigned short* __restrict__ e1h,
                                                 const unsigned short* __restrict__ Bh,
                                                 const float* __restrict__ b1,
                                                 const float* __restrict__ g1,
                                                 const float* __restrict__ bb1,
                                                 const float* __restrict__ m1,
                                                 const float* __restrict__ v1,
                                                 unsigned short* __restrict__ Bmap) {
    __shared__ unsigned short e0s[4][120];
    __shared__ unsigned short e1s[32][120];
    __shared__ float bnb_s[64], sc_s[64], off_s[64];
    int i0 = blockIdx.x * 4, j0 = blockIdx.y * 32;
    int tid = threadIdx.x;
    if (tid < 64) {
        int h = tid < 50 ? tid : 0;
        float sc = g1[h] * rsqrtf(v1[h] + EPS);
        bnb_s[tid] = b1[h];
        sc_s[tid] = sc;
        off_s[tid] = bb1[h] - m1[h] * sc;
    }
    for (int idx = tid; idx < 540; idx += 256) {
        int r = idx / 15, c = idx % 15;
        uint4 v = {0, 0, 0, 0};
        if (c < 14)
            v = (r < 4) ? *(const uint4*)(e0h + (i0 + r) * 112 + c * 8)
                        : *(const uint4*)(e1h + (j0 + r - 4) * 112 + c * 8);
        if (r < 4) *(uint4*)&e0s[r][c * 8] = v;
        else *(uint4*)&e1s[r - 4][c * 8] = v;
    }
    __syncthreads();

    int lane = tid & 63;
    int wid = tid >> 6;        // wave's i offset (0..3)
    int g = lane >> 4;
    int jrow = lane & 15;

    f32x4 acc[2][4] = {};      // [jf][hf]

#pragma unroll
    for (int ks = 0; ks < 8; ++ks) {
        f16x8 b[4];
#pragma unroll
        for (int hf = 0; hf < 4; ++hf) {
            int fidx = ((ks * 4 + hf) * 64 + lane) * 8;
            b[hf] = __builtin_bit_cast(f16x8, *(const uint4*)(Bh + fidx));
        }
        int d0 = (ks & 3) * 32 + g * 8;
        d0 = d0 > 112 ? 112 : d0;
        f16x8 x0 = *(const f16x8*)&e0s[wid][d0];
#pragma unroll
        for (int jf = 0; jf < 2; ++jf) {
            f16x8 x1 = *(const f16x8*)&e1s[jf * 16 + jrow][d0];
            f16x8 a;
            if (ks < 4) {
                f16x8 dd = x0 - x1;
                uint4 u = __builtin_bit_cast(uint4, dd);
                u.x &= 0x7FFF7FFFu; u.y &= 0x7FFF7FFFu;
                u.z &= 0x7FFF7FFFu; u.w &= 0x7FFF7FFFu;
                a = __builtin_bit_cast(f16x8, u);
            } else {
                a = x0 * x1;
            }
#pragma unroll
            for (int hf = 0; hf < 4; ++hf) {
                acc[jf][hf] = __builtin_amdgcn_mfma_f32_16x16x32_f16(
                    a, b[hf], acc[jf][hf], 0, 0, 0);
            }
        }
    }

    // epilogue: D[row=j][col=h]; lane (g,hl): rows j = jf*16 + g*4 + r, col h = hf*16+hl
    int hl = lane & 15;
    int i = i0 + wid;
#pragma unroll
    for (int hf = 0; hf < 4; ++hf) {
        int h = hf * 16 + hl;
        bool ok = h < 50;
        float bnb = bnb_s[h];
        float sc = sc_s[h];
        float off = off_s[h];
#pragma unroll
        for (int jf = 0; jf < 2; ++jf) {
            int j = j0 + jf * 16 + g * 4;
            f32x4 a = acc[jf][hf];
            unsigned short o[4];
#pragma unroll
            for (int r = 0; r < 4; ++r) {
                float x = a[r] + bnb;
                x = elu_f(x);
                x = fmaf(x, sc, off);
                x = elu_f(x);
                o[r] = f16b(x);
            }
            if (ok) {
                *(ushort4*)&Bmap[(size_t)h * PLANE + (size_t)(i + 3) * ST + (j + 32)] =
                    *(ushort4*)o;
            }
        }
    }
}

// ---------------- Kernel 3: 7x7 conv via v_dot2_f32_f16, fp16 LDS, dbuf ----------------
// 1D grid 1690 with XCD-chunked bijective swizzle (q=211, r=2): adjacent tiles
// (sharing halo cache lines) land on the SAME XCD's L2.
__global__ __launch_bounds__(256) void kconv(const unsigned short* __restrict__ Bmap,
                                             const unsigned short* __restrict__ Wq,
                                             unsigned short* __restrict__ CpH) {
    __shared__ unsigned short tile[2][70][80];
    int orig = blockIdx.x;
    int xcd = orig & 7, pos = orig >> 3;
    int t = (xcd < 2) ? xcd * 212 + pos : 424 + (xcd - 2) * 211 + pos;
    int bx = t % 13;
    int t2 = t / 13;
    int by = t2 % 13, zc = t2 / 13;
    int h0 = zc * 5;
    int tid = threadIdx.x;
    int lx = tid & 15, ly = tid >> 4;

    int u0 = tid, u1 = tid + 256, u2 = tid + 512;
    int r0 = u0 / 10, k0 = u0 - r0 * 10;
    int r1 = u1 / 10, k1 = u1 - r1 * 10;
    int r2 = u2 / 10, k2 = u2 - r2 * 10;
    bool has2 = (u2 < 700);
    const unsigned short* base = Bmap + (size_t)h0 * PLANE;
    size_t o0 = (size_t)(64 * by + r0) * ST + 64 * bx + 24 + 8 * k0;
    size_t o1 = (size_t)(64 * by + r1) * ST + 64 * bx + 24 + 8 * k1;
    size_t o2 = (size_t)(64 * by + r2) * ST + 64 * bx + 24 + 8 * k2;

    *(uint4*)&tile[0][r0][8 * k0] = *(const uint4*)(base + o0);
    *(uint4*)&tile[0][r1][8 * k1] = *(const uint4*)(base + o1);
    if (has2) *(uint4*)&tile[0][r2][8 * k2] = *(const uint4*)(base + o2);
    uint4 s0 = *(const uint4*)(base + PLANE + o0);
    uint4 s1 = *(const uint4*)(base + PLANE + o1);
    uint4 s2 = has2 ? *(const uint4*)(base + PLANE + o2) : uint4{0, 0, 0, 0};

    float acc[4][4] = {};
    for (int hh = 0; hh < 5; ++hh) {
        int cur = hh & 1;
        __syncthreads();
        if (hh < 4) {
            *(uint4*)&tile[cur ^ 1][r0][8 * k0] = s0;
            *(uint4*)&tile[cur ^ 1][r1][8 * k1] = s1;
            if (has2) *(uint4*)&tile[cur ^ 1][r2][8 * k2] = s2;
            if (hh < 3) {
                const unsigned short* nb = base + (size_t)(hh + 2) * PLANE;
                s0 = *(const uint4*)(nb + o0);
                s1 = *(const uint4*)(nb + o1);
                if (has2) s2 = *(const uint4*)(nb + o2);
            }
        }
        h2 we[7][4], wo[7][4];
        {
            const uint4* wv = (const uint4*)Wq + (size_t)(h0 + hh) * 14;
#pragma unroll
            for (int di = 0; di < 7; ++di) {
                uint4 a = wv[di];
                we[di][0] = __builtin_bit_cast(h2, a.x);
                we[di][1] = __builtin_bit_cast(h2, a.y);
                we[di][2] = __builtin_bit_cast(h2, a.z);
                we[di][3] = __builtin_bit_cast(h2, a.w);
                uint4 c = wv[7 + di];
                wo[di][0] = __builtin_bit_cast(h2, c.x);
                wo[di][1] = __builtin_bit_cast(h2, c.y);
                wo[di][2] = __builtin_bit_cast(h2, c.z);
                wo[di][3] = __builtin_bit_cast(h2, c.w);
            }
        }
#pragma unroll
        for (int r = 0; r < 10; ++r) {
            const unsigned int* trow = (const unsigned int*)&tile[cur][4 * ly + r][0];
            int mb = 2 * lx + 2;
            uint2 da = *(const uint2*)&trow[mb];
            uint2 db = *(const uint2*)&trow[mb + 2];
            uint2 dc = *(const uint2*)&trow[mb + 4];
            h2 q0 = __builtin_bit_cast(h2, da.x), q1 = __builtin_bit_cast(h2, da.y);
            h2 q2 = __builtin_bit_cast(h2, db.x), q3 = __builtin_bit_cast(h2, db.y);
            h2 q4 = __builtin_bit_cast(h2, dc.x), q5 = __builtin_bit_cast(h2, dc.y);
#pragma unroll
            for (int rr = 0; rr < 4; ++rr) {
                int di = r - rr;
                if (di < 0 || di > 6) continue;
                acc[rr][0] = __builtin_amdgcn_fdot2(q0, wo[di][0],
                             __builtin_amdgcn_fdot2(q1, wo[di][1],
                             __builtin_amdgcn_fdot2(q2, wo[di][2],
                             __builtin_amdgcn_fdot2(q3, wo[di][3], acc[rr][0], false), false), false), false);
                acc[rr][1] = __builtin_amdgcn_fdot2(q1, we[di][0],
                             __builtin_amdgcn_fdot2(q2, we[di][1],
                             __builtin_amdgcn_fdot2(q3, we[di][2],
                             __builtin_amdgcn_fdot2(q4, we[di][3], acc[rr][1], false), false), false), false);
                acc[rr][2] = __builtin_amdgcn_fdot2(q1, wo[di][0],
                             __builtin_amdgcn_fdot2(q2, wo[di][1],
                             __builtin_amdgcn_fdot2(q3, wo[di][2],
                             __builtin_amdgcn_fdot2(q4, wo[di][3], acc[rr][2], false), false), false), false);
                acc[rr][3] = __builtin_amdgcn_fdot2(q2, we[di][0],
                             __builtin_amdgcn_fdot2(q3, we[di][1],
                             __builtin_amdgcn_fdot2(q4, we[di][2],
                             __builtin_amdgcn_fdot2(q5, we[di][3], acc[rr][3], false), false), false), false);
            }
        }
    }
    int j = 64 * bx + 4 * lx;
    if (j < 800) {
#pragma unroll
        for (int rr = 0; rr < 4; ++rr) {
            int i = 64 * by + 4 * ly + rr;
            if (i < 800) {
                unsigned short st[4];
#pragma unroll
                for (int cc = 0; cc < 4; ++cc) st[cc] = f16b(acc[rr][cc]);
                *(ushort4*)&CpH[(size_t)zc * 640000 + (size_t)i * 800 + j] =
                    *(ushort4*)st;
            }
        }
    }
}

// ---------------- Kernel 3b: reduce fp16 partials + bias + bn2 -> f32 C ----------------
__global__ __launch_bounds__(256) void kreduce(const unsigned short* __restrict__ CpH,
                                               const float* __restrict__ b2,
                                               const float* __restrict__ g2,
                                               const float* __restrict__ bb2,
                                               const float* __restrict__ m2,
                                               const float* __restrict__ v2,
                                               float* __restrict__ C) {
    int idx = blockIdx.x * 256 + threadIdx.x;
    if (idx >= 80000) return;
    float s2 = g2[0] * rsqrtf(v2[0] + EPS);
    float t2 = bb2[0] - m2[0] * s2;
    float bias = b2[0];
    float s[8] = {0.f, 0.f, 0.f, 0.f, 0.f, 0.f, 0.f, 0.f};
#pragma unroll
    for (int z = 0; z < 10; z++) {
        uint4 v = ((const uint4*)(CpH + (size_t)z * 640000))[idx];
        h2 p0 = __builtin_bit_cast(h2, v.x), p1 = __builtin_bit_cast(h2, v.y);
        h2 p2 = __builtin_bit_cast(h2, v.z), p3 = __builtin_bit_cast(h2, v.w);
        s[0] += (float)p0[0]; s[1] += (float)p0[1];
        s[2] += (float)p1[0]; s[3] += (float)p1[1];
        s[4] += (float)p2[0]; s[5] += (float)p2[1];
        s[6] += (float)p3[0]; s[7] += (float)p3[1];
    }
    float4 oa, ob;
    oa.x = (s[0] + bias) * s2 + t2; oa.y = (s[1] + bias) * s2 + t2;
    oa.z = (s[2] + bias) * s2 + t2; oa.w = (s[3] + bias) * s2 + t2;
    ob.x = (s[4] + bias) * s2 + t2; ob.y = (s[5] + bias) * s2 + t2;
    ob.z = (s[6] + bias) * s2 + t2; ob.w = (s[7] + bias) * s2 + t2;
    ((float4*)C)[idx * 2] = oa;
    ((float4*)C)[idx * 2 + 1] = ob;
}

// ---------------- Kernel 4: 9x9/9 maxpool with pad 4 -> yhat (89x89) ----------------
__global__ __launch_bounds__(256) void kpool(const float* __restrict__ C,
                                             float* __restrict__ yhat) {
    int idx = blockIdx.x * 256 + threadIdx.x;
    if (idx >= 89 * 89) return;
    int oy = idx / 89, ox = idx % 89;
    float mx = -INFINITY;
    int y0 = oy * 9 - 4, x0 = ox * 9 - 4;
    for (int dy = 0; dy < 9; dy++) {
        int y = y0 + dy;
        if (y < 0 || y >= 800) continue;
        for (int dx = 0; dx < 9; dx++) {
            int x = x0 + dx;
            if (x < 0 || x >= 800) continue;
            mx = fmaxf(mx, C[y * 800 + x]);
        }
    }
    yhat[idx] = mx;
}

// ---------------- Kernel 5: mean/var -> Q -> phat -> gelu ----------------
__global__ __launch_bounds__(256) void kfinal(const float* __restrict__ yhat,
                                              const float* __restrict__ gamma,
                                              float* __restrict__ out) {
    const int N = 89 * 89;
    __shared__ float sA[4], sB[4];
    int tid = threadIdx.x;
    int wid = tid >> 6, lane = tid & 63;
    float s = 0.f, ss = 0.f;
    for (int i = tid; i < N; i += 256) {
        float y = yhat[i];
        s += y;
        ss = fmaf(y, y, ss);
    }
    for (int off = 32; off; off >>= 1) {
        s += __shfl_down(s, off);
        ss += __shfl_down(ss, off);
    }
    if (lane == 0) { sA[wid] = s; sB[wid] = ss; }
    __syncthreads();
    float S = sA[0] + sA[1] + sA[2] + sA[3];
    float SS = sB[0] + sB[1] + sB[2] + sB[3];
    float mu = S / (float)N;
    float var = (SS - S * S / (float)N) / (float)(N - 1);
    float thr = mu + gamma[0] * var;
    __syncthreads();
    float q = 0.f, c = 0.f;
    for (int i = tid; i < N; i += 256) {
        float d = yhat[i] - thr;
        if (d > 0.f) { q += d; c += 1.f; }
    }
    for (int off = 32; off; off >>= 1) {
        q += __shfl_down(q, off);
        c += __shfl_down(c, off);
    }
    if (lane == 0) { sA[wid] = q; sB[wid] = c; }
    __syncthreads();
    if (tid == 0) {
        float Q = sA[0] + sA[1] + sA[2] + sA[3];
        float Cnt = sB[0] + sB[1] + sB[2] + sB[3];
        float phat = Q / (Cnt + 1.f);
        out[0] = 0.5f * phat * (1.f + erff(phat * 0.70710678118654752f));
    }
}

extern "C" void kernel_launch(void* const* d_in, const int* in_sizes, int n_in,
                              void* d_out, int out_size, void* d_ws, size_t ws_size,
                              hipStream_t stream) {
    const float* z0   = (const float*)d_in[0];
    const float* z1   = (const float*)d_in[1];
    const float* Wemb = (const float*)d_in[2];
    const float* bemb = (const float*)d_in[3];
    const float* W1   = (const float*)d_in[4];
    const float* b1   = (const float*)d_in[5];
    const float* bn1g = (const float*)d_in[6];
    const float* bn1b = (const float*)d_in[7];
    const float* bn1m = (const float*)d_in[8];
    const float* bn1v = (const float*)d_in[9];
    const float* W2   = (const float*)d_in[10];
    const float* b2   = (const float*)d_in[11];
    const float* bn2g = (const float*)d_in[12];
    const float* bn2b = (const float*)d_in[13];
    const float* bn2m = (const float*)d_in[14];
    const float* bn2v = (const float*)d_in[15];
    const float* gam  = (const float*)d_in[16];

    unsigned short* e0h  = (unsigned short*)d_ws;               // 800 x 112 fp16
    unsigned short* e1h  = e0h + 89600;
    unsigned short* Bh   = e1h + 89600;                         // 16,384 fp16
    unsigned short* Wq   = Bh + 16384;                          // 5,600 fp16
    unsigned short* Bmap = Wq + 5600;                           // 50 x PLANE fp16
    unsigned short* CpH  = Bmap + (size_t)50 * PLANE;           // 10 x 640,000 fp16
    float* Cbuf = (float*)Bmap;                                 // alias (Bmap dead after kconv)
    float* yhat = Cbuf + 640000;
    float* out  = (float*)d_out;

    kprep<<<1236, 256, 0, stream>>>(z0, z1, Wemb, bemb, e0h, e1h, W1, Bh,
                                    Bmap, W2, Wq);
    dim3 gi(200, 25);
    kinter<<<gi, 256, 0, stream>>>(e0h, e1h, Bh, b1, bn1g, bn1b, bn1m, bn1v, Bmap);
    kconv<<<1690, 256, 0, stream>>>(Bmap, Wq, CpH);
    kreduce<<<(80000 + 255) / 256, 256, 0, stream>>>(CpH, b2, bn2g, bn2b, bn2m, bn2v, Cbuf);
    kpool<<<(89 * 89 + 255) / 256, 256, 0, stream>>>(Cbuf, yhat);
    kfinal<<<1, 256, 0, stream>>>(yhat, gam, out);
}

// Round 15
// 141.568 us; speedup vs baseline: 2.1210x; 2.1210x over previous
//
#include <hip/hip_runtime.h>
#include <hip/hip_bf16.h>
#include <math.h>

#define EPS 1e-5f
#define ST 896                   // padded Bmap row stride (fp16 elems), 64B-multiple
#define PLANE (896 * 806)        // padded plane elems (3+800+3 rows)
#define PLANE4 (PLANE / 8)       // uint4 per plane = 90272

typedef _Float16 f16x8 __attribute__((ext_vector_type(8)));
typedef _Float16 h2 __attribute__((ext_vector_type(2)));
typedef float f32x4 __attribute__((ext_vector_type(4)));

__device__ __forceinline__ float elu_f(float x) {
    return x > 0.f ? x : __expf(x) - 1.f;
}
__device__ __forceinline__ unsigned short f16b(float x) {
    return __builtin_bit_cast(unsigned short, (_Float16)x);
}

// ---- Merged prep ----
// b<100:      kembed via MFMA (16 z-rows/block, e fp16 rows padded to 112)
// 100..163:   kprepW (W1 -> fp16 B-fragments, K=256 split-K layout)
// 164..1232:  kzero  (halo borders of padded Bmap)
// 1233..1235: W2pack (dual-alignment fp16 weight quads)
__global__ __launch_bounds__(256) void kprep(const float* __restrict__ z0,
                                             const float* __restrict__ z1,
                                             const float* __restrict__ Wemb,
                                             const float* __restrict__ bemb,
                                             unsigned short* __restrict__ e0h,
                                             unsigned short* __restrict__ e1h,
                                             const float* __restrict__ W1,
                                             unsigned short* __restrict__ Bh,
                                             unsigned short* __restrict__ Bmap,
                                             const float* __restrict__ W2,
                                             unsigned short* __restrict__ Wq) {
    __shared__ unsigned short zls[16][1032];   // 16 z-rows fp16, padded stride
    int b = blockIdx.x;
    int tid = threadIdx.x;
    if (b < 100) {
        // ---- kembed MFMA: e[m][d] = elu(z[m][:] . Wemb[d][:] + bemb[d]) ----
        int src = b & 1;
        int rowbase = (b >> 1) * 16;
        const float* z = src ? z1 : z0;
        unsigned short* e = src ? e1h : e0h;
        const float4* zr4 = (const float4*)(z + rowbase * 1024);
        for (int idx = tid; idx < 4096; idx += 256) {
            int r = idx >> 8, c = idx & 255;
            float4 v = zr4[idx];
            unsigned int p0 = __builtin_bit_cast(unsigned int,
                __builtin_amdgcn_cvt_pkrtz(v.x, v.y));
            unsigned int p1 = __builtin_bit_cast(unsigned int,
                __builtin_amdgcn_cvt_pkrtz(v.z, v.w));
            uint2 pv = {p0, p1};
            *(uint2*)&zls[r][c * 4] = pv;
        }
        __syncthreads();
        int lane = tid & 63, wid = tid >> 6;
        int g = lane >> 4, rl = lane & 15;
        int mf0 = wid * 2;
        int nfrag = (wid < 3) ? 2 : 1;      // 7 d-frags over 4 waves
        f32x4 acc[2] = {};
        for (int ks = 0; ks < 32; ++ks) {
            f16x8 bz = *(const f16x8*)&zls[rl][ks * 32 + g * 8];
#pragma unroll
            for (int q = 0; q < 2; ++q) {
                if (q < nfrag) {
                    int d = (mf0 + q) * 16 + rl;
                    d = d > 99 ? 99 : d;
                    const float* wp = Wemb + d * 1024 + ks * 32 + g * 8;
                    float4 w0 = *(const float4*)wp;
                    float4 w1 = *(const float4*)(wp + 4);
                    uint4 au;
                    au.x = __builtin_bit_cast(unsigned int,
                        __builtin_amdgcn_cvt_pkrtz(w0.x, w0.y));
                    au.y = __builtin_bit_cast(unsigned int,
                        __builtin_amdgcn_cvt_pkrtz(w0.z, w0.w));
                    au.z = __builtin_bit_cast(unsigned int,
                        __builtin_amdgcn_cvt_pkrtz(w1.x, w1.y));
                    au.w = __builtin_bit_cast(unsigned int,
                        __builtin_amdgcn_cvt_pkrtz(w1.z, w1.w));
                    f16x8 a = __builtin_bit_cast(f16x8, au);
                    acc[q] = __builtin_amdgcn_mfma_f32_16x16x32_f16(a, bz, acc[q], 0, 0, 0);
                }
            }
        }
#pragma unroll
        for (int q = 0; q < 2; ++q) {
            if (q < nfrag) {
                int dbase = (mf0 + q) * 16 + g * 4;
                int zr = rowbase + rl;
                unsigned short o[4];
#pragma unroll
                for (int r = 0; r < 4; ++r) {
                    int d = dbase + r;
                    float be = bemb[d > 99 ? 99 : d];
                    float x = elu_f(acc[q][r] + be);
                    o[r] = (d < 100) ? f16b(x) : (unsigned short)0;
                }
                *(ushort4*)&e[zr * 112 + dbase] = *(ushort4*)o;
            }
        }
    } else if (b < 164) {
        // ---- kprepW: fp16 B-fragments; K=256: k<128 dif(d=k), k>=128 mul(d=k-128) ----
        int idx = (b - 100) * 256 + tid;     // 0..16383
        int i = idx & 7;
        int lane = (idx >> 3) & 63;
        int hf = (idx >> 9) & 3;
        int ks = idx >> 11;                  // 0..7
        int h = hf * 16 + (lane & 15);
        int k = ks * 32 + (lane >> 4) * 8 + i;
        int term = k >> 7;
        int d = k & 127;
        float val = (d < 100 && h < 50) ? W1[h * 200 + term * 100 + d] : 0.f;
        Bh[idx] = f16b(val);
    } else if (b < 1233) {
        // ---- kzero: halo borders of padded Bmap (uint4) ----
        int idx = (b - 164) * 256 + tid;
        if (idx < 273600) {
            int h = idx / 5472, q = idx % 5472;
            int row, colv;
            if (q < 672) {
                int rr = q / 112;
                colv = q - rr * 112;
                row = rr < 3 ? rr : 800 + rr;
            } else {
                int q2 = q - 672;
                row = 3 + q2 / 6;
                int s = q2 % 6;
                colv = (s == 0) ? 3 : 103 + s;
            }
            uint4 zz = {0, 0, 0, 0};
            ((uint4*)Bmap)[(size_t)h * PLANE4 + row * 112 + colv] = zz;
        }
    } else {
        // ---- W2 pack: dual-alignment fp16 weight quads for dot2 conv ----
        int idx = (b - 1233) * 256 + tid;
        if (idx < 700) {
            int h = idx / 14, rem = idx % 14;
            int lay = rem / 7, di = rem % 7;
            const float* wsrc = W2 + h * 49 + di * 7;
            unsigned short wf[8];
            if (lay == 0) {
#pragma unroll
                for (int t = 0; t < 7; t++) wf[t] = f16b(wsrc[t]);
                wf[7] = 0;
            } else {
                wf[0] = 0;
#pragma unroll
                for (int t = 0; t < 7; t++) wf[t + 1] = f16b(wsrc[t]);
            }
            *(uint4*)&Wq[idx * 8] = *(uint4*)wf;
        }
    }
}

// ---------------- Kernel 2: interaction GEMM via MFMA (fp16, split-K 256) ----------------
// grid (200,25), 256 thr = 4 waves. Tile 4 i x 32 j; each wave owns ONE i.
// Per-lane acc = 32 f32 (acc[jf][hf]); bn consts via LDS table.
// NOTE: no min-waves clause — round 14's (256,6) forced 40 VGPRs -> scratch spill
// (WRITE_SIZE 745 MB). Let the allocator pick (~70-80 VGPR, 6 waves/SIMD natural).
__global__ __launch_bounds__(256) void kinter(const unsigned short* __restrict__ e0h,
                                              const unsigned short* __restrict__ e1h,
                                              const unsigned short* __restrict__ Bh,
                                              const float* __restrict__ b1,
                                              const float* __restrict__ g1,
                                              const float* __restrict__ bb1,
                                              const float* __restrict__ m1,
                                              const float* __restrict__ v1,
                                              unsigned short* __restrict__ Bmap) {
    __shared__ unsigned short e0s[4][120];
    __shared__ unsigned short e1s[32][120];
    __shared__ float bnb_s[64], sc_s[64], off_s[64];
    int i0 = blockIdx.x * 4, j0 = blockIdx.y * 32;
    int tid = threadIdx.x;
    if (tid < 64) {
        int h = tid < 50 ? tid : 0;
        float sc = g1[h] * rsqrtf(v1[h] + EPS);
        bnb_s[tid] = b1[h];
        sc_s[tid] = sc;
        off_s[tid] = bb1[h] - m1[h] * sc;
    }
    for (int idx = tid; idx < 540; idx += 256) {
        int r = idx / 15, c = idx % 15;
        uint4 v = {0, 0, 0, 0};
        if (c < 14)
            v = (r < 4) ? *(const uint4*)(e0h + (i0 + r) * 112 + c * 8)
                        : *(const uint4*)(e1h + (j0 + r - 4) * 112 + c * 8);
        if (r < 4) *(uint4*)&e0s[r][c * 8] = v;
        else *(uint4*)&e1s[r - 4][c * 8] = v;
    }
    __syncthreads();

    int lane = tid & 63;
    int wid = tid >> 6;        // wave's i offset (0..3)
    int g = lane >> 4;
    int jrow = lane & 15;

    f32x4 acc[2][4] = {};      // [jf][hf]

#pragma unroll
    for (int ks = 0; ks < 8; ++ks) {
        f16x8 b[4];
#pragma unroll
        for (int hf = 0; hf < 4; ++hf) {
            int fidx = ((ks * 4 + hf) * 64 + lane) * 8;
            b[hf] = __builtin_bit_cast(f16x8, *(const uint4*)(Bh + fidx));
        }
        int d0 = (ks & 3) * 32 + g * 8;
        d0 = d0 > 112 ? 112 : d0;
        f16x8 x0 = *(const f16x8*)&e0s[wid][d0];
#pragma unroll
        for (int jf = 0; jf < 2; ++jf) {
            f16x8 x1 = *(const f16x8*)&e1s[jf * 16 + jrow][d0];
            f16x8 a;
            if (ks < 4) {
                f16x8 dd = x0 - x1;
                uint4 u = __builtin_bit_cast(uint4, dd);
                u.x &= 0x7FFF7FFFu; u.y &= 0x7FFF7FFFu;
                u.z &= 0x7FFF7FFFu; u.w &= 0x7FFF7FFFu;
                a = __builtin_bit_cast(f16x8, u);
            } else {
                a = x0 * x1;
            }
#pragma unroll
            for (int hf = 0; hf < 4; ++hf) {
                acc[jf][hf] = __builtin_amdgcn_mfma_f32_16x16x32_f16(
                    a, b[hf], acc[jf][hf], 0, 0, 0);
            }
        }
    }

    // epilogue: D[row=j][col=h]; lane (g,hl): rows j = jf*16 + g*4 + r, col h = hf*16+hl
    int hl = lane & 15;
    int i = i0 + wid;
#pragma unroll
    for (int hf = 0; hf < 4; ++hf) {
        int h = hf * 16 + hl;
        bool ok = h < 50;
        float bnb = bnb_s[h];
        float sc = sc_s[h];
        float off = off_s[h];
#pragma unroll
        for (int jf = 0; jf < 2; ++jf) {
            int j = j0 + jf * 16 + g * 4;
            f32x4 a = acc[jf][hf];
            unsigned short o[4];
#pragma unroll
            for (int r = 0; r < 4; ++r) {
                float x = a[r] + bnb;
                x = elu_f(x);
                x = fmaf(x, sc, off);
                x = elu_f(x);
                o[r] = f16b(x);
            }
            if (ok) {
                *(ushort4*)&Bmap[(size_t)h * PLANE + (size_t)(i + 3) * ST + (j + 32)] =
                    *(ushort4*)o;
            }
        }
    }
}

// ---------------- Kernel 3: 7x7 conv via v_dot2_f32_f16, fp16 LDS, dbuf ----------------
// 1D grid 1690 with XCD-chunked bijective swizzle (q=211, r=2): adjacent tiles
// (sharing halo cache lines) land on the SAME XCD's L2.
__global__ __launch_bounds__(256) void kconv(const unsigned short* __restrict__ Bmap,
                                             const unsigned short* __restrict__ Wq,
                                             unsigned short* __restrict__ CpH) {
    __shared__ unsigned short tile[2][70][80];
    int orig = blockIdx.x;
    int xcd = orig & 7, pos = orig >> 3;
    int t = (xcd < 2) ? xcd * 212 + pos : 424 + (xcd - 2) * 211 + pos;
    int bx = t % 13;
    int t2 = t / 13;
    int by = t2 % 13, zc = t2 / 13;
    int h0 = zc * 5;
    int tid = threadIdx.x;
    int lx = tid & 15, ly = tid >> 4;

    int u0 = tid, u1 = tid + 256, u2 = tid + 512;
    int r0 = u0 / 10, k0 = u0 - r0 * 10;
    int r1 = u1 / 10, k1 = u1 - r1 * 10;
    int r2 = u2 / 10, k2 = u2 - r2 * 10;
    bool has2 = (u2 < 700);
    const unsigned short* base = Bmap + (size_t)h0 * PLANE;
    size_t o0 = (size_t)(64 * by + r0) * ST + 64 * bx + 24 + 8 * k0;
    size_t o1 = (size_t)(64 * by + r1) * ST + 64 * bx + 24 + 8 * k1;
    size_t o2 = (size_t)(64 * by + r2) * ST + 64 * bx + 24 + 8 * k2;

    *(uint4*)&tile[0][r0][8 * k0] = *(const uint4*)(base + o0);
    *(uint4*)&tile[0][r1][8 * k1] = *(const uint4*)(base + o1);
    if (has2) *(uint4*)&tile[0][r2][8 * k2] = *(const uint4*)(base + o2);
    uint4 s0 = *(const uint4*)(base + PLANE + o0);
    uint4 s1 = *(const uint4*)(base + PLANE + o1);
    uint4 s2 = has2 ? *(const uint4*)(base + PLANE + o2) : uint4{0, 0, 0, 0};

    float acc[4][4] = {};
    for (int hh = 0; hh < 5; ++hh) {
        int cur = hh & 1;
        __syncthreads();
        if (hh < 4) {
            *(uint4*)&tile[cur ^ 1][r0][8 * k0] = s0;
            *(uint4*)&tile[cur ^ 1][r1][8 * k1] = s1;
            if (has2) *(uint4*)&tile[cur ^ 1][r2][8 * k2] = s2;
            if (hh < 3) {
                const unsigned short* nb = base + (size_t)(hh + 2) * PLANE;
                s0 = *(const uint4*)(nb + o0);
                s1 = *(const uint4*)(nb + o1);
                if (has2) s2 = *(const uint4*)(nb + o2);
            }
        }
        h2 we[7][4], wo[7][4];
        {
            const uint4* wv = (const uint4*)Wq + (size_t)(h0 + hh) * 14;
#pragma unroll
            for (int di = 0; di < 7; ++di) {
                uint4 a = wv[di];
                we[di][0] = __builtin_bit_cast(h2, a.x);
                we[di][1] = __builtin_bit_cast(h2, a.y);
                we[di][2] = __builtin_bit_cast(h2, a.z);
                we[di][3] = __builtin_bit_cast(h2, a.w);
                uint4 c = wv[7 + di];
                wo[di][0] = __builtin_bit_cast(h2, c.x);
                wo[di][1] = __builtin_bit_cast(h2, c.y);
                wo[di][2] = __builtin_bit_cast(h2, c.z);
                wo[di][3] = __builtin_bit_cast(h2, c.w);
            }
        }
#pragma unroll
        for (int r = 0; r < 10; ++r) {
            const unsigned int* trow = (const unsigned int*)&tile[cur][4 * ly + r][0];
            int mb = 2 * lx + 2;
            uint2 da = *(const uint2*)&trow[mb];
            uint2 db = *(const uint2*)&trow[mb + 2];
            uint2 dc = *(const uint2*)&trow[mb + 4];
            h2 q0 = __builtin_bit_cast(h2, da.x), q1 = __builtin_bit_cast(h2, da.y);
            h2 q2 = __builtin_bit_cast(h2, db.x), q3 = __builtin_bit_cast(h2, db.y);
            h2 q4 = __builtin_bit_cast(h2, dc.x), q5 = __builtin_bit_cast(h2, dc.y);
#pragma unroll
            for (int rr = 0; rr < 4; ++rr) {
                int di = r - rr;
                if (di < 0 || di > 6) continue;
                acc[rr][0] = __builtin_amdgcn_fdot2(q0, wo[di][0],
                             __builtin_amdgcn_fdot2(q1, wo[di][1],
                             __builtin_amdgcn_fdot2(q2, wo[di][2],
                             __builtin_amdgcn_fdot2(q3, wo[di][3], acc[rr][0], false), false), false), false);
                acc[rr][1] = __builtin_amdgcn_fdot2(q1, we[di][0],
                             __builtin_amdgcn_fdot2(q2, we[di][1],
                             __builtin_amdgcn_fdot2(q3, we[di][2],
                             __builtin_amdgcn_fdot2(q4, we[di][3], acc[rr][1], false), false), false), false);
                acc[rr][2] = __builtin_amdgcn_fdot2(q1, wo[di][0],
                             __builtin_amdgcn_fdot2(q2, wo[di][1],
                             __builtin_amdgcn_fdot2(q3, wo[di][2],
                             __builtin_amdgcn_fdot2(q4, wo[di][3], acc[rr][2], false), false), false), false);
                acc[rr][3] = __builtin_amdgcn_fdot2(q2, we[di][0],
                             __builtin_amdgcn_fdot2(q3, we[di][1],
                             __builtin_amdgcn_fdot2(q4, we[di][2],
                             __builtin_amdgcn_fdot2(q5, we[di][3], acc[rr][3], false), false), false), false);
            }
        }
    }
    int j = 64 * bx + 4 * lx;
    if (j < 800) {
#pragma unroll
        for (int rr = 0; rr < 4; ++rr) {
            int i = 64 * by + 4 * ly + rr;
            if (i < 800) {
                unsigned short st[4];
#pragma unroll
                for (int cc = 0; cc < 4; ++cc) st[cc] = f16b(acc[rr][cc]);
                *(ushort4*)&CpH[(size_t)zc * 640000 + (size_t)i * 800 + j] =
                    *(ushort4*)st;
            }
        }
    }
}

// ---------------- Kernel 3b: reduce fp16 partials + bias + bn2 -> f32 C ----------------
__global__ __launch_bounds__(256) void kreduce(const unsigned short* __restrict__ CpH,
                                               const float* __restrict__ b2,
                                               const float* __restrict__ g2,
                                               const float* __restrict__ bb2,
                                               const float* __restrict__ m2,
                                               const float* __restrict__ v2,
                                               float* __restrict__ C) {
    int idx = blockIdx.x * 256 + threadIdx.x;
    if (idx >= 80000) return;
    float s2 = g2[0] * rsqrtf(v2[0] + EPS);
    float t2 = bb2[0] - m2[0] * s2;
    float bias = b2[0];
    float s[8] = {0.f, 0.f, 0.f, 0.f, 0.f, 0.f, 0.f, 0.f};
#pragma unroll
    for (int z = 0; z < 10; z++) {
        uint4 v = ((const uint4*)(CpH + (size_t)z * 640000))[idx];
        h2 p0 = __builtin_bit_cast(h2, v.x), p1 = __builtin_bit_cast(h2, v.y);
        h2 p2 = __builtin_bit_cast(h2, v.z), p3 = __builtin_bit_cast(h2, v.w);
        s[0] += (float)p0[0]; s[1] += (float)p0[1];
        s[2] += (float)p1[0]; s[3] += (float)p1[1];
        s[4] += (float)p2[0]; s[5] += (float)p2[1];
        s[6] += (float)p3[0]; s[7] += (float)p3[1];
    }
    float4 oa, ob;
    oa.x = (s[0] + bias) * s2 + t2; oa.y = (s[1] + bias) * s2 + t2;
    oa.z = (s[2] + bias) * s2 + t2; oa.w = (s[3] + bias) * s2 + t2;
    ob.x = (s[4] + bias) * s2 + t2; ob.y = (s[5] + bias) * s2 + t2;
    ob.z = (s[6] + bias) * s2 + t2; ob.w = (s[7] + bias) * s2 + t2;
    ((float4*)C)[idx * 2] = oa;
    ((float4*)C)[idx * 2 + 1] = ob;
}

// ---------------- Kernel 4: 9x9/9 maxpool with pad 4 -> yhat (89x89) ----------------
__global__ __launch_bounds__(256) void kpool(const float* __restrict__ C,
                                             float* __restrict__ yhat) {
    int idx = blockIdx.x * 256 + threadIdx.x;
    if (idx >= 89 * 89) return;
    int oy = idx / 89, ox = idx % 89;
    float mx = -INFINITY;
    int y0 = oy * 9 - 4, x0 = ox * 9 - 4;
    for (int dy = 0; dy < 9; dy++) {
        int y = y0 + dy;
        if (y < 0 || y >= 800) continue;
        for (int dx = 0; dx < 9; dx++) {
            int x = x0 + dx;
            if (x < 0 || x >= 800) continue;
            mx = fmaxf(mx, C[y * 800 + x]);
        }
    }
    yhat[idx] = mx;
}

// ---------------- Kernel 5: mean/var -> Q -> phat -> gelu ----------------
__global__ __launch_bounds__(256) void kfinal(const float* __restrict__ yhat,
                                              const float* __restrict__ gamma,
                                              float* __restrict__ out) {
    const int N = 89 * 89;
    __shared__ float sA[4], sB[4];
    int tid = threadIdx.x;
    int wid = tid >> 6, lane = tid & 63;
    float s = 0.f, ss = 0.f;
    for (int i = tid; i < N; i += 256) {
        float y = yhat[i];
        s += y;
        ss = fmaf(y, y, ss);
    }
    for (int off = 32; off; off >>= 1) {
        s += __shfl_down(s, off);
        ss += __shfl_down(ss, off);
    }
    if (lane == 0) { sA[wid] = s; sB[wid] = ss; }
    __syncthreads();
    float S = sA[0] + sA[1] + sA[2] + sA[3];
    float SS = sB[0] + sB[1] + sB[2] + sB[3];
    float mu = S / (float)N;
    float var = (SS - S * S / (float)N) / (float)(N - 1);
    float thr = mu + gamma[0] * var;
    __syncthreads();
    float q = 0.f, c = 0.f;
    for (int i = tid; i < N; i += 256) {
        float d = yhat[i] - thr;
        if (d > 0.f) { q += d; c += 1.f; }
    }
    for (int off = 32; off; off >>= 1) {
        q += __shfl_down(q, off);
        c += __shfl_down(c, off);
    }
    if (lane == 0) { sA[wid] = q; sB[wid] = c; }
    __syncthreads();
    if (tid == 0) {
        float Q = sA[0] + sA[1] + sA[2] + sA[3];
        float Cnt = sB[0] + sB[1] + sB[2] + sB[3];
        float phat = Q / (Cnt + 1.f);
        out[0] = 0.5f * phat * (1.f + erff(phat * 0.70710678118654752f));
    }
}

extern "C" void kernel_launch(void* const* d_in, const int* in_sizes, int n_in,
                              void* d_out, int out_size, void* d_ws, size_t ws_size,
                              hipStream_t stream) {
    const float* z0   = (const float*)d_in[0];
    const float* z1   = (const float*)d_in[1];
    const float* Wemb = (const float*)d_in[2];
    const float* bemb = (const float*)d_in[3];
    const float* W1   = (const float*)d_in[4];
    const float* b1   = (const float*)d_in[5];
    const float* bn1g = (const float*)d_in[6];
    const float* bn1b = (const float*)d_in[7];
    const float* bn1m = (const float*)d_in[8];
    const float* bn1v = (const float*)d_in[9];
    const float* W2   = (const float*)d_in[10];
    const float* b2   = (const float*)d_in[11];
    const float* bn2g = (const float*)d_in[12];
    const float* bn2b = (const float*)d_in[13];
    const float* bn2m = (const float*)d_in[14];
    const float* bn2v = (const float*)d_in[15];
    const float* gam  = (const float*)d_in[16];

    unsigned short* e0h  = (unsigned short*)d_ws;               // 800 x 112 fp16
    unsigned short* e1h  = e0h + 89600;
    unsigned short* Bh   = e1h + 89600;                         // 16,384 fp16
    unsigned short* Wq   = Bh + 16384;                          // 5,600 fp16
    unsigned short* Bmap = Wq + 5600;                           // 50 x PLANE fp16
    unsigned short* CpH  = Bmap + (size_t)50 * PLANE;           // 10 x 640,000 fp16
    float* Cbuf = (float*)Bmap;                                 // alias (Bmap dead after kconv)
    float* yhat = Cbuf + 640000;
    float* out  = (float*)d_out;

    kprep<<<1236, 256, 0, stream>>>(z0, z1, Wemb, bemb, e0h, e1h, W1, Bh,
                                    Bmap, W2, Wq);
    dim3 gi(200, 25);
    kinter<<<gi, 256, 0, stream>>>(e0h, e1h, Bh, b1, bn1g, bn1b, bn1m, bn1v, Bmap);
    kconv<<<1690, 256, 0, stream>>>(Bmap, Wq, CpH);
    kreduce<<<(80000 + 255) / 256, 256, 0, stream>>>(CpH, b2, bn2g, bn2b, bn2m, bn2v, Cbuf);
    kpool<<<(89 * 89 + 255) / 256, 256, 0, stream>>>(Cbuf, yhat);
    kfinal<<<1, 256, 0, stream>>>(yhat, gam, out);
}

// Round 16
// 138.687 us; speedup vs baseline: 2.1651x; 1.0208x over previous
//
#include <hip/hip_runtime.h>
#include <hip/hip_bf16.h>
#include <math.h>

#define EPS 1e-5f
#define ST 896                   // padded Bmap row stride (fp16 elems), 64B-multiple
#define PLANE (896 * 806)        // padded plane elems (3+800+3 rows)
#define PLANE4 (PLANE / 8)       // uint4 per plane = 90272

typedef _Float16 f16x8 __attribute__((ext_vector_type(8)));
typedef _Float16 h2 __attribute__((ext_vector_type(2)));
typedef float f32x4 __attribute__((ext_vector_type(4)));

__device__ __forceinline__ float elu_f(float x) {
    return x > 0.f ? x : __expf(x) - 1.f;
}
__device__ __forceinline__ unsigned short f16b(float x) {
    return __builtin_bit_cast(unsigned short, (_Float16)x);
}

// ---- Merged prep ----
// b<100:      kembed via MFMA (16 z-rows/block, e fp16 rows padded to 112)
// 100..163:   kprepW (W1 -> fp16 B-fragments, K=256 split-K layout)
// 164..1232:  kzero  (halo borders of padded Bmap)
// 1233..1235: W2pack (dual-alignment fp16 weight quads)
__global__ __launch_bounds__(256) void kprep(const float* __restrict__ z0,
                                             const float* __restrict__ z1,
                                             const float* __restrict__ Wemb,
                                             const float* __restrict__ bemb,
                                             unsigned short* __restrict__ e0h,
                                             unsigned short* __restrict__ e1h,
                                             const float* __restrict__ W1,
                                             unsigned short* __restrict__ Bh,
                                             unsigned short* __restrict__ Bmap,
                                             const float* __restrict__ W2,
                                             unsigned short* __restrict__ Wq) {
    __shared__ unsigned short zls[16][1032];   // 16 z-rows fp16, padded stride
    int b = blockIdx.x;
    int tid = threadIdx.x;
    if (b < 100) {
        // ---- kembed MFMA: e[m][d] = elu(z[m][:] . Wemb[d][:] + bemb[d]) ----
        int src = b & 1;
        int rowbase = (b >> 1) * 16;
        const float* z = src ? z1 : z0;
        unsigned short* e = src ? e1h : e0h;
        const float4* zr4 = (const float4*)(z + rowbase * 1024);
        for (int idx = tid; idx < 4096; idx += 256) {
            int r = idx >> 8, c = idx & 255;
            float4 v = zr4[idx];
            unsigned int p0 = __builtin_bit_cast(unsigned int,
                __builtin_amdgcn_cvt_pkrtz(v.x, v.y));
            unsigned int p1 = __builtin_bit_cast(unsigned int,
                __builtin_amdgcn_cvt_pkrtz(v.z, v.w));
            uint2 pv = {p0, p1};
            *(uint2*)&zls[r][c * 4] = pv;
        }
        __syncthreads();
        int lane = tid & 63, wid = tid >> 6;
        int g = lane >> 4, rl = lane & 15;
        int mf0 = wid * 2;
        int nfrag = (wid < 3) ? 2 : 1;      // 7 d-frags over 4 waves
        f32x4 acc[2] = {};
        for (int ks = 0; ks < 32; ++ks) {
            f16x8 bz = *(const f16x8*)&zls[rl][ks * 32 + g * 8];
#pragma unroll
            for (int q = 0; q < 2; ++q) {
                if (q < nfrag) {
                    int d = (mf0 + q) * 16 + rl;
                    d = d > 99 ? 99 : d;
                    const float* wp = Wemb + d * 1024 + ks * 32 + g * 8;
                    float4 w0 = *(const float4*)wp;
                    float4 w1 = *(const float4*)(wp + 4);
                    uint4 au;
                    au.x = __builtin_bit_cast(unsigned int,
                        __builtin_amdgcn_cvt_pkrtz(w0.x, w0.y));
                    au.y = __builtin_bit_cast(unsigned int,
                        __builtin_amdgcn_cvt_pkrtz(w0.z, w0.w));
                    au.z = __builtin_bit_cast(unsigned int,
                        __builtin_amdgcn_cvt_pkrtz(w1.x, w1.y));
                    au.w = __builtin_bit_cast(unsigned int,
                        __builtin_amdgcn_cvt_pkrtz(w1.z, w1.w));
                    f16x8 a = __builtin_bit_cast(f16x8, au);
                    acc[q] = __builtin_amdgcn_mfma_f32_16x16x32_f16(a, bz, acc[q], 0, 0, 0);
                }
            }
        }
#pragma unroll
        for (int q = 0; q < 2; ++q) {
            if (q < nfrag) {
                int dbase = (mf0 + q) * 16 + g * 4;
                int zr = rowbase + rl;
                unsigned short o[4];
#pragma unroll
                for (int r = 0; r < 4; ++r) {
                    int d = dbase + r;
                    float be = bemb[d > 99 ? 99 : d];
                    float x = elu_f(acc[q][r] + be);
                    o[r] = (d < 100) ? f16b(x) : (unsigned short)0;
                }
                *(ushort4*)&e[zr * 112 + dbase] = *(ushort4*)o;
            }
        }
    } else if (b < 164) {
        // ---- kprepW: fp16 B-fragments; K=256: k<128 dif(d=k), k>=128 mul(d=k-128) ----
        int idx = (b - 100) * 256 + tid;     // 0..16383
        int i = idx & 7;
        int lane = (idx >> 3) & 63;
        int hf = (idx >> 9) & 3;
        int ks = idx >> 11;                  // 0..7
        int h = hf * 16 + (lane & 15);
        int k = ks * 32 + (lane >> 4) * 8 + i;
        int term = k >> 7;
        int d = k & 127;
        float val = (d < 100 && h < 50) ? W1[h * 200 + term * 100 + d] : 0.f;
        Bh[idx] = f16b(val);
    } else if (b < 1233) {
        // ---- kzero: halo borders of padded Bmap (uint4) ----
        int idx = (b - 164) * 256 + tid;
        if (idx < 273600) {
            int h = idx / 5472, q = idx % 5472;
            int row, colv;
            if (q < 672) {
                int rr = q / 112;
                colv = q - rr * 112;
                row = rr < 3 ? rr : 800 + rr;
            } else {
                int q2 = q - 672;
                row = 3 + q2 / 6;
                int s = q2 % 6;
                colv = (s == 0) ? 3 : 103 + s;
            }
            uint4 zz = {0, 0, 0, 0};
            ((uint4*)Bmap)[(size_t)h * PLANE4 + row * 112 + colv] = zz;
        }
    } else {
        // ---- W2 pack: dual-alignment fp16 weight quads for dot2 conv ----
        int idx = (b - 1233) * 256 + tid;
        if (idx < 700) {
            int h = idx / 14, rem = idx % 14;
            int lay = rem / 7, di = rem % 7;
            const float* wsrc = W2 + h * 49 + di * 7;
            unsigned short wf[8];
            if (lay == 0) {
#pragma unroll
                for (int t = 0; t < 7; t++) wf[t] = f16b(wsrc[t]);
                wf[7] = 0;
            } else {
                wf[0] = 0;
#pragma unroll
                for (int t = 0; t < 7; t++) wf[t + 1] = f16b(wsrc[t]);
            }
            *(uint4*)&Wq[idx * 8] = *(uint4*)wf;
        }
    }
}

// ---------------- Kernel 2: interaction GEMM via MFMA (fp16, split-K 256) ----------------
// grid (200,25), 256 thr = 4 waves. Tile 4 i x 32 j; each wave owns ONE i.
// NEW: Bh fragment table staged into LDS once per block (32KB) — kills the
// 640 MB of per-wave L2 re-reads and the per-ks global-load latency chain.
__global__ __launch_bounds__(256) void kinter(const unsigned short* __restrict__ e0h,
                                              const unsigned short* __restrict__ e1h,
                                              const unsigned short* __restrict__ Bh,
                                              const float* __restrict__ b1,
                                              const float* __restrict__ g1,
                                              const float* __restrict__ bb1,
                                              const float* __restrict__ m1,
                                              const float* __restrict__ v1,
                                              unsigned short* __restrict__ Bmap) {
    __shared__ unsigned short Bhs[16384];     // 32 KB fragment table
    __shared__ unsigned short e0s[4][120];
    __shared__ unsigned short e1s[32][120];
    __shared__ float bnb_s[64], sc_s[64], off_s[64];
    int i0 = blockIdx.x * 4, j0 = blockIdx.y * 32;
    int tid = threadIdx.x;
    if (tid < 64) {
        int h = tid < 50 ? tid : 0;
        float sc = g1[h] * rsqrtf(v1[h] + EPS);
        bnb_s[tid] = b1[h];
        sc_s[tid] = sc;
        off_s[tid] = bb1[h] - m1[h] * sc;
    }
#pragma unroll
    for (int q = 0; q < 8; ++q) {
        int idx = q * 256 + tid;
        ((uint4*)Bhs)[idx] = ((const uint4*)Bh)[idx];
    }
    for (int idx = tid; idx < 540; idx += 256) {
        int r = idx / 15, c = idx % 15;
        uint4 v = {0, 0, 0, 0};
        if (c < 14)
            v = (r < 4) ? *(const uint4*)(e0h + (i0 + r) * 112 + c * 8)
                        : *(const uint4*)(e1h + (j0 + r - 4) * 112 + c * 8);
        if (r < 4) *(uint4*)&e0s[r][c * 8] = v;
        else *(uint4*)&e1s[r - 4][c * 8] = v;
    }
    __syncthreads();

    int lane = tid & 63;
    int wid = tid >> 6;        // wave's i offset (0..3)
    int g = lane >> 4;
    int jrow = lane & 15;

    f32x4 acc[2][4] = {};      // [jf][hf]

#pragma unroll
    for (int ks = 0; ks < 8; ++ks) {
        f16x8 b[4];
#pragma unroll
        for (int hf = 0; hf < 4; ++hf) {
            int fidx = ((ks * 4 + hf) * 64 + lane) * 8;
            b[hf] = *(const f16x8*)&Bhs[fidx];   // contiguous ds_read_b128, conflict-free
        }
        int d0 = (ks & 3) * 32 + g * 8;
        d0 = d0 > 112 ? 112 : d0;
        f16x8 x0 = *(const f16x8*)&e0s[wid][d0];
#pragma unroll
        for (int jf = 0; jf < 2; ++jf) {
            f16x8 x1 = *(const f16x8*)&e1s[jf * 16 + jrow][d0];
            f16x8 a;
            if (ks < 4) {
                f16x8 dd = x0 - x1;
                uint4 u = __builtin_bit_cast(uint4, dd);
                u.x &= 0x7FFF7FFFu; u.y &= 0x7FFF7FFFu;
                u.z &= 0x7FFF7FFFu; u.w &= 0x7FFF7FFFu;
                a = __builtin_bit_cast(f16x8, u);
            } else {
                a = x0 * x1;
            }
#pragma unroll
            for (int hf = 0; hf < 4; ++hf) {
                acc[jf][hf] = __builtin_amdgcn_mfma_f32_16x16x32_f16(
                    a, b[hf], acc[jf][hf], 0, 0, 0);
            }
        }
    }

    // epilogue: D[row=j][col=h]; lane (g,hl): rows j = jf*16 + g*4 + r, col h = hf*16+hl
    int hl = lane & 15;
    int i = i0 + wid;
#pragma unroll
    for (int hf = 0; hf < 4; ++hf) {
        int h = hf * 16 + hl;
        bool ok = h < 50;
        float bnb = bnb_s[h];
        float sc = sc_s[h];
        float off = off_s[h];
#pragma unroll
        for (int jf = 0; jf < 2; ++jf) {
            int j = j0 + jf * 16 + g * 4;
            f32x4 a = acc[jf][hf];
            unsigned short o[4];
#pragma unroll
            for (int r = 0; r < 4; ++r) {
                float x = a[r] + bnb;
                x = elu_f(x);
                x = fmaf(x, sc, off);
                x = elu_f(x);
                o[r] = f16b(x);
            }
            if (ok) {
                *(ushort4*)&Bmap[(size_t)h * PLANE + (size_t)(i + 3) * ST + (j + 32)] =
                    *(ushort4*)o;
            }
        }
    }
}

// ---------------- Kernel 3: 7x7 conv via v_dot2_f32_f16, fp16 LDS, dbuf ----------------
// 1D grid 1690 with XCD-chunked bijective swizzle (q=211, r=2): adjacent tiles
// (sharing halo cache lines) land on the SAME XCD's L2.
__global__ __launch_bounds__(256) void kconv(const unsigned short* __restrict__ Bmap,
                                             const unsigned short* __restrict__ Wq,
                                             unsigned short* __restrict__ CpH) {
    __shared__ unsigned short tile[2][70][80];
    int orig = blockIdx.x;
    int xcd = orig & 7, pos = orig >> 3;
    int t = (xcd < 2) ? xcd * 212 + pos : 424 + (xcd - 2) * 211 + pos;
    int bx = t % 13;
    int t2 = t / 13;
    int by = t2 % 13, zc = t2 / 13;
    int h0 = zc * 5;
    int tid = threadIdx.x;
    int lx = tid & 15, ly = tid >> 4;

    int u0 = tid, u1 = tid + 256, u2 = tid + 512;
    int r0 = u0 / 10, k0 = u0 - r0 * 10;
    int r1 = u1 / 10, k1 = u1 - r1 * 10;
    int r2 = u2 / 10, k2 = u2 - r2 * 10;
    bool has2 = (u2 < 700);
    const unsigned short* base = Bmap + (size_t)h0 * PLANE;
    size_t o0 = (size_t)(64 * by + r0) * ST + 64 * bx + 24 + 8 * k0;
    size_t o1 = (size_t)(64 * by + r1) * ST + 64 * bx + 24 + 8 * k1;
    size_t o2 = (size_t)(64 * by + r2) * ST + 64 * bx + 24 + 8 * k2;

    *(uint4*)&tile[0][r0][8 * k0] = *(const uint4*)(base + o0);
    *(uint4*)&tile[0][r1][8 * k1] = *(const uint4*)(base + o1);
    if (has2) *(uint4*)&tile[0][r2][8 * k2] = *(const uint4*)(base + o2);
    uint4 s0 = *(const uint4*)(base + PLANE + o0);
    uint4 s1 = *(const uint4*)(base + PLANE + o1);
    uint4 s2 = has2 ? *(const uint4*)(base + PLANE + o2) : uint4{0, 0, 0, 0};

    float acc[4][4] = {};
    for (int hh = 0; hh < 5; ++hh) {
        int cur = hh & 1;
        __syncthreads();
        if (hh < 4) {
            *(uint4*)&tile[cur ^ 1][r0][8 * k0] = s0;
            *(uint4*)&tile[cur ^ 1][r1][8 * k1] = s1;
            if (has2) *(uint4*)&tile[cur ^ 1][r2][8 * k2] = s2;
            if (hh < 3) {
                const unsigned short* nb = base + (size_t)(hh + 2) * PLANE;
                s0 = *(const uint4*)(nb + o0);
                s1 = *(const uint4*)(nb + o1);
                if (has2) s2 = *(const uint4*)(nb + o2);
            }
        }
        h2 we[7][4], wo[7][4];
        {
            const uint4* wv = (const uint4*)Wq + (size_t)(h0 + hh) * 14;
#pragma unroll
            for (int di = 0; di < 7; ++di) {
                uint4 a = wv[di];
                we[di][0] = __builtin_bit_cast(h2, a.x);
                we[di][1] = __builtin_bit_cast(h2, a.y);
                we[di][2] = __builtin_bit_cast(h2, a.z);
                we[di][3] = __builtin_bit_cast(h2, a.w);
                uint4 c = wv[7 + di];
                wo[di][0] = __builtin_bit_cast(h2, c.x);
                wo[di][1] = __builtin_bit_cast(h2, c.y);
                wo[di][2] = __builtin_bit_cast(h2, c.z);
                wo[di][3] = __builtin_bit_cast(h2, c.w);
            }
        }
#pragma unroll
        for (int r = 0; r < 10; ++r) {
            const unsigned int* trow = (const unsigned int*)&tile[cur][4 * ly + r][0];
            int mb = 2 * lx + 2;
            uint2 da = *(const uint2*)&trow[mb];
            uint2 db = *(const uint2*)&trow[mb + 2];
            uint2 dc = *(const uint2*)&trow[mb + 4];
            h2 q0 = __builtin_bit_cast(h2, da.x), q1 = __builtin_bit_cast(h2, da.y);
            h2 q2 = __builtin_bit_cast(h2, db.x), q3 = __builtin_bit_cast(h2, db.y);
            h2 q4 = __builtin_bit_cast(h2, dc.x), q5 = __builtin_bit_cast(h2, dc.y);
#pragma unroll
            for (int rr = 0; rr < 4; ++rr) {
                int di = r - rr;
                if (di < 0 || di > 6) continue;
                acc[rr][0] = __builtin_amdgcn_fdot2(q0, wo[di][0],
                             __builtin_amdgcn_fdot2(q1, wo[di][1],
                             __builtin_amdgcn_fdot2(q2, wo[di][2],
                             __builtin_amdgcn_fdot2(q3, wo[di][3], acc[rr][0], false), false), false), false);
                acc[rr][1] = __builtin_amdgcn_fdot2(q1, we[di][0],
                             __builtin_amdgcn_fdot2(q2, we[di][1],
                             __builtin_amdgcn_fdot2(q3, we[di][2],
                             __builtin_amdgcn_fdot2(q4, we[di][3], acc[rr][1], false), false), false), false);
                acc[rr][2] = __builtin_amdgcn_fdot2(q1, wo[di][0],
                             __builtin_amdgcn_fdot2(q2, wo[di][1],
                             __builtin_amdgcn_fdot2(q3, wo[di][2],
                             __builtin_amdgcn_fdot2(q4, wo[di][3], acc[rr][2], false), false), false), false);
                acc[rr][3] = __builtin_amdgcn_fdot2(q2, we[di][0],
                             __builtin_amdgcn_fdot2(q3, we[di][1],
                             __builtin_amdgcn_fdot2(q4, we[di][2],
                             __builtin_amdgcn_fdot2(q5, we[di][3], acc[rr][3], false), false), false), false);
            }
        }
    }
    int j = 64 * bx + 4 * lx;
    if (j < 800) {
#pragma unroll
        for (int rr = 0; rr < 4; ++rr) {
            int i = 64 * by + 4 * ly + rr;
            if (i < 800) {
                unsigned short st[4];
#pragma unroll
                for (int cc = 0; cc < 4; ++cc) st[cc] = f16b(acc[rr][cc]);
                *(ushort4*)&CpH[(size_t)zc * 640000 + (size_t)i * 800 + j] =
                    *(ushort4*)st;
            }
        }
    }
}

// ---------------- Kernel 3b: reduce fp16 partials + bias + bn2 -> f32 C ----------------
__global__ __launch_bounds__(256) void kreduce(const unsigned short* __restrict__ CpH,
                                               const float* __restrict__ b2,
                                               const float* __restrict__ g2,
                                               const float* __restrict__ bb2,
                                               const float* __restrict__ m2,
                                               const float* __restrict__ v2,
                                               float* __restrict__ C) {
    int idx = blockIdx.x * 256 + threadIdx.x;
    if (idx >= 80000) return;
    float s2 = g2[0] * rsqrtf(v2[0] + EPS);
    float t2 = bb2[0] - m2[0] * s2;
    float bias = b2[0];
    float s[8] = {0.f, 0.f, 0.f, 0.f, 0.f, 0.f, 0.f, 0.f};
#pragma unroll
    for (int z = 0; z < 10; z++) {
        uint4 v = ((const uint4*)(CpH + (size_t)z * 640000))[idx];
        h2 p0 = __builtin_bit_cast(h2, v.x), p1 = __builtin_bit_cast(h2, v.y);
        h2 p2 = __builtin_bit_cast(h2, v.z), p3 = __builtin_bit_cast(h2, v.w);
        s[0] += (float)p0[0]; s[1] += (float)p0[1];
        s[2] += (float)p1[0]; s[3] += (float)p1[1];
        s[4] += (float)p2[0]; s[5] += (float)p2[1];
        s[6] += (float)p3[0]; s[7] += (float)p3[1];
    }
    float4 oa, ob;
    oa.x = (s[0] + bias) * s2 + t2; oa.y = (s[1] + bias) * s2 + t2;
    oa.z = (s[2] + bias) * s2 + t2; oa.w = (s[3] + bias) * s2 + t2;
    ob.x = (s[4] + bias) * s2 + t2; ob.y = (s[5] + bias) * s2 + t2;
    ob.z = (s[6] + bias) * s2 + t2; ob.w = (s[7] + bias) * s2 + t2;
    ((float4*)C)[idx * 2] = oa;
    ((float4*)C)[idx * 2 + 1] = ob;
}

// ---------------- Kernel 4: 9x9/9 maxpool with pad 4 -> yhat (89x89) ----------------
__global__ __launch_bounds__(256) void kpool(const float* __restrict__ C,
                                             float* __restrict__ yhat) {
    int idx = blockIdx.x * 256 + threadIdx.x;
    if (idx >= 89 * 89) return;
    int oy = idx / 89, ox = idx % 89;
    float mx = -INFINITY;
    int y0 = oy * 9 - 4, x0 = ox * 9 - 4;
    for (int dy = 0; dy < 9; dy++) {
        int y = y0 + dy;
        if (y < 0 || y >= 800) continue;
        for (int dx = 0; dx < 9; dx++) {
            int x = x0 + dx;
            if (x < 0 || x >= 800) continue;
            mx = fmaxf(mx, C[y * 800 + x]);
        }
    }
    yhat[idx] = mx;
}

// ---------------- Kernel 5: mean/var -> Q -> phat -> gelu ----------------
__global__ __launch_bounds__(256) void kfinal(const float* __restrict__ yhat,
                                              const float* __restrict__ gamma,
                                              float* __restrict__ out) {
    const int N = 89 * 89;
    __shared__ float sA[4], sB[4];
    int tid = threadIdx.x;
    int wid = tid >> 6, lane = tid & 63;
    float s = 0.f, ss = 0.f;
    for (int i = tid; i < N; i += 256) {
        float y = yhat[i];
        s += y;
        ss = fmaf(y, y, ss);
    }
    for (int off = 32; off; off >>= 1) {
        s += __shfl_down(s, off);
        ss += __shfl_down(ss, off);
    }
    if (lane == 0) { sA[wid] = s; sB[wid] = ss; }
    __syncthreads();
    float S = sA[0] + sA[1] + sA[2] + sA[3];
    float SS = sB[0] + sB[1] + sB[2] + sB[3];
    float mu = S / (float)N;
    float var = (SS - S * S / (float)N) / (float)(N - 1);
    float thr = mu + gamma[0] * var;
    __syncthreads();
    float q = 0.f, c = 0.f;
    for (int i = tid; i < N; i += 256) {
        float d = yhat[i] - thr;
        if (d > 0.f) { q += d; c += 1.f; }
    }
    for (int off = 32; off; off >>= 1) {
        q += __shfl_down(q, off);
        c += __shfl_down(c, off);
    }
    if (lane == 0) { sA[wid] = q; sB[wid] = c; }
    __syncthreads();
    if (tid == 0) {
        float Q = sA[0] + sA[1] + sA[2] + sA[3];
        float Cnt = sB[0] + sB[1] + sB[2] + sB[3];
        float phat = Q / (Cnt + 1.f);
        out[0] = 0.5f * phat * (1.f + erff(phat * 0.70710678118654752f));
    }
}

extern "C" void kernel_launch(void* const* d_in, const int* in_sizes, int n_in,
                              void* d_out, int out_size, void* d_ws, size_t ws_size,
                              hipStream_t stream) {
    const float* z0   = (const float*)d_in[0];
    const float* z1   = (const float*)d_in[1];
    const float* Wemb = (const float*)d_in[2];
    const float* bemb = (const float*)d_in[3];
    const float* W1   = (const float*)d_in[4];
    const float* b1   = (const float*)d_in[5];
    const float* bn1g = (const float*)d_in[6];
    const float* bn1b = (const float*)d_in[7];
    const float* bn1m = (const float*)d_in[8];
    const float* bn1v = (const float*)d_in[9];
    const float* W2   = (const float*)d_in[10];
    const float* b2   = (const float*)d_in[11];
    const float* bn2g = (const float*)d_in[12];
    const float* bn2b = (const float*)d_in[13];
    const float* bn2m = (const float*)d_in[14];
    const float* bn2v = (const float*)d_in[15];
    const float* gam  = (const float*)d_in[16];

    unsigned short* e0h  = (unsigned short*)d_ws;               // 800 x 112 fp16
    unsigned short* e1h  = e0h + 89600;
    unsigned short* Bh   = e1h + 89600;                         // 16,384 fp16
    unsigned short* Wq   = Bh + 16384;                          // 5,600 fp16
    unsigned short* Bmap = Wq + 5600;                           // 50 x PLANE fp16
    unsigned short* CpH  = Bmap + (size_t)50 * PLANE;           // 10 x 640,000 fp16
    float* Cbuf = (float*)Bmap;                                 // alias (Bmap dead after kconv)
    float* yhat = Cbuf + 640000;
    float* out  = (float*)d_out;

    kprep<<<1236, 256, 0, stream>>>(z0, z1, Wemb, bemb, e0h, e1h, W1, Bh,
                                    Bmap, W2, Wq);
    dim3 gi(200, 25);
    kinter<<<gi, 256, 0, stream>>>(e0h, e1h, Bh, b1, bn1g, bn1b, bn1m, bn1v, Bmap);
    kconv<<<1690, 256, 0, stream>>>(Bmap, Wq, CpH);
    kreduce<<<(80000 + 255) / 256, 256, 0, stream>>>(CpH, b2, bn2g, bn2b, bn2m, bn2v, Cbuf);
    kpool<<<(89 * 89 + 255) / 256, 256, 0, stream>>>(Cbuf, yhat);
    kfinal<<<1, 256, 0, stream>>>(yhat, gam, out);
}

// Round 17
// 128.968 us; speedup vs baseline: 2.3283x; 1.0754x over previous
//
#include <hip/hip_runtime.h>
#include <hip/hip_bf16.h>
#include <math.h>

#define EPS 1e-5f
#define ST 896                   // padded Bmap row stride (fp16 elems), 64B-multiple
#define PLANE (896 * 806)        // padded plane elems (3+800+3 rows)
#define PLANE4 (PLANE / 8)       // uint4 per plane = 90272

typedef _Float16 f16x8 __attribute__((ext_vector_type(8)));
typedef _Float16 h2 __attribute__((ext_vector_type(2)));
typedef float f32x4 __attribute__((ext_vector_type(4)));

__device__ __forceinline__ float elu_f(float x) {
    return x > 0.f ? x : __expf(x) - 1.f;
}
__device__ __forceinline__ unsigned short f16b(float x) {
    return __builtin_bit_cast(unsigned short, (_Float16)x);
}

// ---- Merged prep ----
// b<200:      kembed via MFMA, d-split: src=b&1, dhalf=(b>>1)&1, rowgrp=b>>2 (16 rows)
// 200..263:   kprepW (W1 -> fp16 B-fragments, K=256 split-K layout)
// 264..1332:  kzero  (halo borders of padded Bmap)
// 1333..1335: W2pack (dual-alignment fp16 weight quads)
__global__ __launch_bounds__(256) void kprep(const float* __restrict__ z0,
                                             const float* __restrict__ z1,
                                             const float* __restrict__ Wemb,
                                             const float* __restrict__ bemb,
                                             unsigned short* __restrict__ e0h,
                                             unsigned short* __restrict__ e1h,
                                             const float* __restrict__ W1,
                                             unsigned short* __restrict__ Bh,
                                             unsigned short* __restrict__ Bmap,
                                             const float* __restrict__ W2,
                                             unsigned short* __restrict__ Wq) {
    __shared__ unsigned short zls[16][1032];   // 16 z-rows fp16, padded stride
    int b = blockIdx.x;
    int tid = threadIdx.x;
    if (b < 200) {
        // ---- kembed MFMA: e[m][d] = elu(z[m][:] . Wemb[d][:] + bemb[d]) ----
        int src = b & 1;
        int dh = (b >> 1) & 1;              // d-half: 0 -> frags 0..3, 1 -> frags 4..6
        int rowbase = (b >> 2) * 16;
        const float* z = src ? z1 : z0;
        unsigned short* e = src ? e1h : e0h;
        const float4* zr4 = (const float4*)(z + rowbase * 1024);
        for (int idx = tid; idx < 4096; idx += 256) {
            int r = idx >> 8, c = idx & 255;
            float4 v = zr4[idx];
            unsigned int p0 = __builtin_bit_cast(unsigned int,
                __builtin_amdgcn_cvt_pkrtz(v.x, v.y));
            unsigned int p1 = __builtin_bit_cast(unsigned int,
                __builtin_amdgcn_cvt_pkrtz(v.z, v.w));
            uint2 pv = {p0, p1};
            *(uint2*)&zls[r][c * 4] = pv;
        }
        __syncthreads();
        int lane = tid & 63, wid = tid >> 6;
        int g = lane >> 4, rl = lane & 15;
        int mf = dh == 0 ? wid : 4 + wid;   // this wave's d-frag
        bool active = (mf < 7);
        f32x4 acc = {};
        if (active) {
            for (int ks = 0; ks < 32; ++ks) {
                f16x8 bz = *(const f16x8*)&zls[rl][ks * 32 + g * 8];
                int d = mf * 16 + rl;
                d = d > 99 ? 99 : d;
                const float* wp = Wemb + d * 1024 + ks * 32 + g * 8;
                float4 w0 = *(const float4*)wp;
                float4 w1 = *(const float4*)(wp + 4);
                uint4 au;
                au.x = __builtin_bit_cast(unsigned int,
                    __builtin_amdgcn_cvt_pkrtz(w0.x, w0.y));
                au.y = __builtin_bit_cast(unsigned int,
                    __builtin_amdgcn_cvt_pkrtz(w0.z, w0.w));
                au.z = __builtin_bit_cast(unsigned int,
                    __builtin_amdgcn_cvt_pkrtz(w1.x, w1.y));
                au.w = __builtin_bit_cast(unsigned int,
                    __builtin_amdgcn_cvt_pkrtz(w1.z, w1.w));
                f16x8 a = __builtin_bit_cast(f16x8, au);
                acc = __builtin_amdgcn_mfma_f32_16x16x32_f16(a, bz, acc, 0, 0, 0);
            }
            int dbase = mf * 16 + g * 4;
            int zr = rowbase + rl;
            unsigned short o[4];
#pragma unroll
            for (int r = 0; r < 4; ++r) {
                int d = dbase + r;
                float be = bemb[d > 99 ? 99 : d];
                float x = elu_f(acc[r] + be);
                o[r] = (d < 100) ? f16b(x) : (unsigned short)0;
            }
            *(ushort4*)&e[zr * 112 + dbase] = *(ushort4*)o;
        }
    } else if (b < 264) {
        // ---- kprepW: fp16 B-fragments; K=256: k<128 dif(d=k), k>=128 mul(d=k-128) ----
        int idx = (b - 200) * 256 + tid;     // 0..16383
        int i = idx & 7;
        int lane = (idx >> 3) & 63;
        int hf = (idx >> 9) & 3;
        int ks = idx >> 11;                  // 0..7
        int h = hf * 16 + (lane & 15);
        int k = ks * 32 + (lane >> 4) * 8 + i;
        int term = k >> 7;
        int d = k & 127;
        float val = (d < 100 && h < 50) ? W1[h * 200 + term * 100 + d] : 0.f;
        Bh[idx] = f16b(val);
    } else if (b < 1333) {
        // ---- kzero: halo borders of padded Bmap (uint4) ----
        int idx = (b - 264) * 256 + tid;
        if (idx < 273600) {
            int h = idx / 5472, q = idx % 5472;
            int row, colv;
            if (q < 672) {
                int rr = q / 112;
                colv = q - rr * 112;
                row = rr < 3 ? rr : 800 + rr;
            } else {
                int q2 = q - 672;
                row = 3 + q2 / 6;
                int s = q2 % 6;
                colv = (s == 0) ? 3 : 103 + s;
            }
            uint4 zz = {0, 0, 0, 0};
            ((uint4*)Bmap)[(size_t)h * PLANE4 + row * 112 + colv] = zz;
        }
    } else {
        // ---- W2 pack: dual-alignment fp16 weight quads for dot2 conv ----
        int idx = (b - 1333) * 256 + tid;
        if (idx < 700) {
            int h = idx / 14, rem = idx % 14;
            int lay = rem / 7, di = rem % 7;
            const float* wsrc = W2 + h * 49 + di * 7;
            unsigned short wf[8];
            if (lay == 0) {
#pragma unroll
                for (int t = 0; t < 7; t++) wf[t] = f16b(wsrc[t]);
                wf[7] = 0;
            } else {
                wf[0] = 0;
#pragma unroll
                for (int t = 0; t < 7; t++) wf[t + 1] = f16b(wsrc[t]);
            }
            *(uint4*)&Wq[idx * 8] = *(uint4*)wf;
        }
    }
}

// ---------------- Kernel 2: interaction GEMM via MFMA (fp16, split-K 256) ----------------
// grid (200,25), 256 thr = 4 waves. Tile 4 i x 32 j; each wave owns ONE i.
// Bh fragment table staged into LDS once per block.
__global__ __launch_bounds__(256) void kinter(const unsigned short* __restrict__ e0h,
                                              const unsigned short* __restrict__ e1h,
                                              const unsigned short* __restrict__ Bh,
                                              const float* __restrict__ b1,
                                              const float* __restrict__ g1,
                                              const float* __restrict__ bb1,
                                              const float* __restrict__ m1,
                                              const float* __restrict__ v1,
                                              unsigned short* __restrict__ Bmap) {
    __shared__ unsigned short Bhs[16384];     // 32 KB fragment table
    __shared__ unsigned short e0s[4][120];
    __shared__ unsigned short e1s[32][120];
    __shared__ float bnb_s[64], sc_s[64], off_s[64];
    int i0 = blockIdx.x * 4, j0 = blockIdx.y * 32;
    int tid = threadIdx.x;
    if (tid < 64) {
        int h = tid < 50 ? tid : 0;
        float sc = g1[h] * rsqrtf(v1[h] + EPS);
        bnb_s[tid] = b1[h];
        sc_s[tid] = sc;
        off_s[tid] = bb1[h] - m1[h] * sc;
    }
#pragma unroll
    for (int q = 0; q < 8; ++q) {
        int idx = q * 256 + tid;
        ((uint4*)Bhs)[idx] = ((const uint4*)Bh)[idx];
    }
    for (int idx = tid; idx < 540; idx += 256) {
        int r = idx / 15, c = idx % 15;
        uint4 v = {0, 0, 0, 0};
        if (c < 14)
            v = (r < 4) ? *(const uint4*)(e0h + (i0 + r) * 112 + c * 8)
                        : *(const uint4*)(e1h + (j0 + r - 4) * 112 + c * 8);
        if (r < 4) *(uint4*)&e0s[r][c * 8] = v;
        else *(uint4*)&e1s[r - 4][c * 8] = v;
    }
    __syncthreads();

    int lane = tid & 63;
    int wid = tid >> 6;        // wave's i offset (0..3)
    int g = lane >> 4;
    int jrow = lane & 15;

    f32x4 acc[2][4] = {};      // [jf][hf]

#pragma unroll
    for (int ks = 0; ks < 8; ++ks) {
        f16x8 b[4];
#pragma unroll
        for (int hf = 0; hf < 4; ++hf) {
            int fidx = ((ks * 4 + hf) * 64 + lane) * 8;
            b[hf] = *(const f16x8*)&Bhs[fidx];
        }
        int d0 = (ks & 3) * 32 + g * 8;
        d0 = d0 > 112 ? 112 : d0;
        f16x8 x0 = *(const f16x8*)&e0s[wid][d0];
#pragma unroll
        for (int jf = 0; jf < 2; ++jf) {
            f16x8 x1 = *(const f16x8*)&e1s[jf * 16 + jrow][d0];
            f16x8 a;
            if (ks < 4) {
                f16x8 dd = x0 - x1;
                uint4 u = __builtin_bit_cast(uint4, dd);
                u.x &= 0x7FFF7FFFu; u.y &= 0x7FFF7FFFu;
                u.z &= 0x7FFF7FFFu; u.w &= 0x7FFF7FFFu;
                a = __builtin_bit_cast(f16x8, u);
            } else {
                a = x0 * x1;
            }
#pragma unroll
            for (int hf = 0; hf < 4; ++hf) {
                acc[jf][hf] = __builtin_amdgcn_mfma_f32_16x16x32_f16(
                    a, b[hf], acc[jf][hf], 0, 0, 0);
            }
        }
    }

    int hl = lane & 15;
    int i = i0 + wid;
#pragma unroll
    for (int hf = 0; hf < 4; ++hf) {
        int h = hf * 16 + hl;
        bool ok = h < 50;
        float bnb = bnb_s[h];
        float sc = sc_s[h];
        float off = off_s[h];
#pragma unroll
        for (int jf = 0; jf < 2; ++jf) {
            int j = j0 + jf * 16 + g * 4;
            f32x4 a = acc[jf][hf];
            unsigned short o[4];
#pragma unroll
            for (int r = 0; r < 4; ++r) {
                float x = a[r] + bnb;
                x = elu_f(x);
                x = fmaf(x, sc, off);
                x = elu_f(x);
                o[r] = f16b(x);
            }
            if (ok) {
                *(ushort4*)&Bmap[(size_t)h * PLANE + (size_t)(i + 3) * ST + (j + 32)] =
                    *(ushort4*)o;
            }
        }
    }
}

// ---------------- Kernel 3: 7x7 conv via v_dot2_f32_f16, fp16 LDS, dbuf ----------------
// grid 845 (13x13x5), chunks of 10 channels -> 5 partial planes.
// XCD-chunked bijective swizzle (845 = 8*105 + 5).
__global__ __launch_bounds__(256) void kconv(const unsigned short* __restrict__ Bmap,
                                             const unsigned short* __restrict__ Wq,
                                             unsigned short* __restrict__ CpH) {
    __shared__ unsigned short tile[2][70][80];
    int orig = blockIdx.x;
    int xcd = orig & 7, pos = orig >> 3;
    int t = (xcd < 5) ? xcd * 106 + pos : 530 + (xcd - 5) * 105 + pos;
    int bx = t % 13;
    int t2 = t / 13;
    int by = t2 % 13, zc = t2 / 13;
    int h0 = zc * 10;
    int tid = threadIdx.x;
    int lx = tid & 15, ly = tid >> 4;

    int u0 = tid, u1 = tid + 256, u2 = tid + 512;
    int r0 = u0 / 10, k0 = u0 - r0 * 10;
    int r1 = u1 / 10, k1 = u1 - r1 * 10;
    int r2 = u2 / 10, k2 = u2 - r2 * 10;
    bool has2 = (u2 < 700);
    const unsigned short* base = Bmap + (size_t)h0 * PLANE;
    size_t o0 = (size_t)(64 * by + r0) * ST + 64 * bx + 24 + 8 * k0;
    size_t o1 = (size_t)(64 * by + r1) * ST + 64 * bx + 24 + 8 * k1;
    size_t o2 = (size_t)(64 * by + r2) * ST + 64 * bx + 24 + 8 * k2;

    *(uint4*)&tile[0][r0][8 * k0] = *(const uint4*)(base + o0);
    *(uint4*)&tile[0][r1][8 * k1] = *(const uint4*)(base + o1);
    if (has2) *(uint4*)&tile[0][r2][8 * k2] = *(const uint4*)(base + o2);
    uint4 s0 = *(const uint4*)(base + PLANE + o0);
    uint4 s1 = *(const uint4*)(base + PLANE + o1);
    uint4 s2 = has2 ? *(const uint4*)(base + PLANE + o2) : uint4{0, 0, 0, 0};

    float acc[4][4] = {};
    for (int hh = 0; hh < 10; ++hh) {
        int cur = hh & 1;
        __syncthreads();
        if (hh < 9) {
            *(uint4*)&tile[cur ^ 1][r0][8 * k0] = s0;
            *(uint4*)&tile[cur ^ 1][r1][8 * k1] = s1;
            if (has2) *(uint4*)&tile[cur ^ 1][r2][8 * k2] = s2;
            if (hh < 8) {
                const unsigned short* nb = base + (size_t)(hh + 2) * PLANE;
                s0 = *(const uint4*)(nb + o0);
                s1 = *(const uint4*)(nb + o1);
                if (has2) s2 = *(const uint4*)(nb + o2);
            }
        }
        h2 we[7][4], wo[7][4];
        {
            const uint4* wv = (const uint4*)Wq + (size_t)(h0 + hh) * 14;
#pragma unroll
            for (int di = 0; di < 7; ++di) {
                uint4 a = wv[di];
                we[di][0] = __builtin_bit_cast(h2, a.x);
                we[di][1] = __builtin_bit_cast(h2, a.y);
                we[di][2] = __builtin_bit_cast(h2, a.z);
                we[di][3] = __builtin_bit_cast(h2, a.w);
                uint4 c = wv[7 + di];
                wo[di][0] = __builtin_bit_cast(h2, c.x);
                wo[di][1] = __builtin_bit_cast(h2, c.y);
                wo[di][2] = __builtin_bit_cast(h2, c.z);
                wo[di][3] = __builtin_bit_cast(h2, c.w);
            }
        }
#pragma unroll
        for (int r = 0; r < 10; ++r) {
            const unsigned int* trow = (const unsigned int*)&tile[cur][4 * ly + r][0];
            int mb = 2 * lx + 2;
            uint2 da = *(const uint2*)&trow[mb];
            uint2 db = *(const uint2*)&trow[mb + 2];
            uint2 dc = *(const uint2*)&trow[mb + 4];
            h2 q0 = __builtin_bit_cast(h2, da.x), q1 = __builtin_bit_cast(h2, da.y);
            h2 q2 = __builtin_bit_cast(h2, db.x), q3 = __builtin_bit_cast(h2, db.y);
            h2 q4 = __builtin_bit_cast(h2, dc.x), q5 = __builtin_bit_cast(h2, dc.y);
#pragma unroll
            for (int rr = 0; rr < 4; ++rr) {
                int di = r - rr;
                if (di < 0 || di > 6) continue;
                acc[rr][0] = __builtin_amdgcn_fdot2(q0, wo[di][0],
                             __builtin_amdgcn_fdot2(q1, wo[di][1],
                             __builtin_amdgcn_fdot2(q2, wo[di][2],
                             __builtin_amdgcn_fdot2(q3, wo[di][3], acc[rr][0], false), false), false), false);
                acc[rr][1] = __builtin_amdgcn_fdot2(q1, we[di][0],
                             __builtin_amdgcn_fdot2(q2, we[di][1],
                             __builtin_amdgcn_fdot2(q3, we[di][2],
                             __builtin_amdgcn_fdot2(q4, we[di][3], acc[rr][1], false), false), false), false);
                acc[rr][2] = __builtin_amdgcn_fdot2(q1, wo[di][0],
                             __builtin_amdgcn_fdot2(q2, wo[di][1],
                             __builtin_amdgcn_fdot2(q3, wo[di][2],
                             __builtin_amdgcn_fdot2(q4, wo[di][3], acc[rr][2], false), false), false), false);
                acc[rr][3] = __builtin_amdgcn_fdot2(q2, we[di][0],
                             __builtin_amdgcn_fdot2(q3, we[di][1],
                             __builtin_amdgcn_fdot2(q4, we[di][2],
                             __builtin_amdgcn_fdot2(q5, we[di][3], acc[rr][3], false), false), false), false);
            }
        }
    }
    int j = 64 * bx + 4 * lx;
    if (j < 800) {
#pragma unroll
        for (int rr = 0; rr < 4; ++rr) {
            int i = 64 * by + 4 * ly + rr;
            if (i < 800) {
                unsigned short st[4];
#pragma unroll
                for (int cc = 0; cc < 4; ++cc) st[cc] = f16b(acc[rr][cc]);
                *(ushort4*)&CpH[(size_t)zc * 640000 + (size_t)i * 800 + j] =
                    *(ushort4*)st;
            }
        }
    }
}

// ---------------- Kernel 3b: reduce fp16 partials + bias + bn2 -> f32 C ----------------
__global__ __launch_bounds__(256) void kreduce(const unsigned short* __restrict__ CpH,
                                               const float* __restrict__ b2,
                                               const float* __restrict__ g2,
                                               const float* __restrict__ bb2,
                                               const float* __restrict__ m2,
                                               const float* __restrict__ v2,
                                               float* __restrict__ C) {
    int idx = blockIdx.x * 256 + threadIdx.x;
    if (idx >= 80000) return;
    float s2 = g2[0] * rsqrtf(v2[0] + EPS);
    float t2 = bb2[0] - m2[0] * s2;
    float bias = b2[0];
    float s[8] = {0.f, 0.f, 0.f, 0.f, 0.f, 0.f, 0.f, 0.f};
#pragma unroll
    for (int z = 0; z < 5; z++) {
        uint4 v = ((const uint4*)(CpH + (size_t)z * 640000))[idx];
        h2 p0 = __builtin_bit_cast(h2, v.x), p1 = __builtin_bit_cast(h2, v.y);
        h2 p2 = __builtin_bit_cast(h2, v.z), p3 = __builtin_bit_cast(h2, v.w);
        s[0] += (float)p0[0]; s[1] += (float)p0[1];
        s[2] += (float)p1[0]; s[3] += (float)p1[1];
        s[4] += (float)p2[0]; s[5] += (float)p2[1];
        s[6] += (float)p3[0]; s[7] += (float)p3[1];
    }
    float4 oa, ob;
    oa.x = (s[0] + bias) * s2 + t2; oa.y = (s[1] + bias) * s2 + t2;
    oa.z = (s[2] + bias) * s2 + t2; oa.w = (s[3] + bias) * s2 + t2;
    ob.x = (s[4] + bias) * s2 + t2; ob.y = (s[5] + bias) * s2 + t2;
    ob.z = (s[6] + bias) * s2 + t2; ob.w = (s[7] + bias) * s2 + t2;
    ((float4*)C)[idx * 2] = oa;
    ((float4*)C)[idx * 2 + 1] = ob;
}

// ---------------- Kernel 4: 9x9/9 maxpool with pad 4 -> yhat (89x89) ----------------
__global__ __launch_bounds__(256) void kpool(const float* __restrict__ C,
                                             float* __restrict__ yhat) {
    int idx = blockIdx.x * 256 + threadIdx.x;
    if (idx >= 89 * 89) return;
    int oy = idx / 89, ox = idx % 89;
    float mx = -INFINITY;
    int y0 = oy * 9 - 4, x0 = ox * 9 - 4;
    for (int dy = 0; dy < 9; dy++) {
        int y = y0 + dy;
        if (y < 0 || y >= 800) continue;
        for (int dx = 0; dx < 9; dx++) {
            int x = x0 + dx;
            if (x < 0 || x >= 800) continue;
            mx = fmaxf(mx, C[y * 800 + x]);
        }
    }
    yhat[idx] = mx;
}

// ---------------- Kernel 5: mean/var -> Q -> phat -> gelu ----------------
__global__ __launch_bounds__(256) void kfinal(const float* __restrict__ yhat,
                                              const float* __restrict__ gamma,
                                              float* __restrict__ out) {
    const int N = 89 * 89;
    __shared__ float sA[4], sB[4];
    int tid = threadIdx.x;
    int wid = tid >> 6, lane = tid & 63;
    float s = 0.f, ss = 0.f;
    for (int i = tid; i < N; i += 256) {
        float y = yhat[i];
        s += y;
        ss = fmaf(y, y, ss);
    }
    for (int off = 32; off; off >>= 1) {
        s += __shfl_down(s, off);
        ss += __shfl_down(ss, off);
    }
    if (lane == 0) { sA[wid] = s; sB[wid] = ss; }
    __syncthreads();
    float S = sA[0] + sA[1] + sA[2] + sA[3];
    float SS = sB[0] + sB[1] + sB[2] + sB[3];
    float mu = S / (float)N;
    float var = (SS - S * S / (float)N) / (float)(N - 1);
    float thr = mu + gamma[0] * var;
    __syncthreads();
    float q = 0.f, c = 0.f;
    for (int i = tid; i < N; i += 256) {
        float d = yhat[i] - thr;
        if (d > 0.f) { q += d; c += 1.f; }
    }
    for (int off = 32; off; off >>= 1) {
        q += __shfl_down(q, off);
        c += __shfl_down(c, off);
    }
    if (lane == 0) { sA[wid] = q; sB[wid] = c; }
    __syncthreads();
    if (tid == 0) {
        float Q = sA[0] + sA[1] + sA[2] + sA[3];
        float Cnt = sB[0] + sB[1] + sB[2] + sB[3];
        float phat = Q / (Cnt + 1.f);
        out[0] = 0.5f * phat * (1.f + erff(phat * 0.70710678118654752f));
    }
}

extern "C" void kernel_launch(void* const* d_in, const int* in_sizes, int n_in,
                              void* d_out, int out_size, void* d_ws, size_t ws_size,
                              hipStream_t stream) {
    const float* z0   = (const float*)d_in[0];
    const float* z1   = (const float*)d_in[1];
    const float* Wemb = (const float*)d_in[2];
    const float* bemb = (const float*)d_in[3];
    const float* W1   = (const float*)d_in[4];
    const float* b1   = (const float*)d_in[5];
    const float* bn1g = (const float*)d_in[6];
    const float* bn1b = (const float*)d_in[7];
    const float* bn1m = (const float*)d_in[8];
    const float* bn1v = (const float*)d_in[9];
    const float* W2   = (const float*)d_in[10];
    const float* b2   = (const float*)d_in[11];
    const float* bn2g = (const float*)d_in[12];
    const float* bn2b = (const float*)d_in[13];
    const float* bn2m = (const float*)d_in[14];
    const float* bn2v = (const float*)d_in[15];
    const float* gam  = (const float*)d_in[16];

    unsigned short* e0h  = (unsigned short*)d_ws;               // 800 x 112 fp16
    unsigned short* e1h  = e0h + 89600;
    unsigned short* Bh   = e1h + 89600;                         // 16,384 fp16
    unsigned short* Wq   = Bh + 16384;                          // 5,600 fp16
    unsigned short* Bmap = Wq + 5600;                           // 50 x PLANE fp16
    unsigned short* CpH  = Bmap + (size_t)50 * PLANE;           // 5 x 640,000 fp16
    float* Cbuf = (float*)Bmap;                                 // alias (Bmap dead after kconv)
    float* yhat = Cbuf + 640000;
    float* out  = (float*)d_out;

    kprep<<<1336, 256, 0, stream>>>(z0, z1, Wemb, bemb, e0h, e1h, W1, Bh,
                                    Bmap, W2, Wq);
    dim3 gi(200, 25);
    kinter<<<gi, 256, 0, stream>>>(e0h, e1h, Bh, b1, bn1g, bn1b, bn1m, bn1v, Bmap);
    kconv<<<845, 256, 0, stream>>>(Bmap, Wq, CpH);
    kreduce<<<(80000 + 255) / 256, 256, 0, stream>>>(CpH, b2, bn2g, bn2b, bn2m, bn2v, Cbuf);
    kpool<<<(89 * 89 + 255) / 256, 256, 0, stream>>>(Cbuf, yhat);
    kfinal<<<1, 256, 0, stream>>>(yhat, gam, out);
}